// Round 13
// baseline (4909.663 us; speedup 1.0000x reference)
//
#include <hip/hip_runtime.h>
#include <hip/hip_bf16.h>
#include <limits.h>
#include <cstddef>

// Problem constants
#define B_SZ    2
#define N_PTS   32768
#define N_KP    2048
#define N_CHUNK 512            // 32768 / 64 points per chunk
#define H_BEV   200
#define W_BEV   176
#define C_BEV   256
#define FEAT_DIM 288
#define C_OUT   128
#define M_ROWS  4096           // B_SZ * N_KP

// Exact-rounding squared distance matching numpy: ((dx*dx + dy*dy) + dz*dz),
// adds protected from FMA contraction.
__device__ __forceinline__ float sqd(float ax, float ay, float az,
                                     float bx, float by, float bz) {
  float dx = ax - bx, dy = ay - by, dz = az - bz;
  return __fadd_rn(__fadd_rn(dx * dx, dy * dy), dz * dz);
}

__device__ __forceinline__ unsigned part1by1(unsigned n) {
  n &= 0xFFFF;
  n = (n | (n << 8)) & 0x00FF00FF;
  n = (n | (n << 4)) & 0x0F0F0F0F;
  n = (n | (n << 2)) & 0x33333333;
  n = (n | (n << 1)) & 0x55555555;
  return n;
}

// ---- DPP wave64 64-bit lexicographic max reduce (VALU pipe) ---------------
// row_shr 1/2/4/8 then row_bcast:15, row_bcast:31; result in lane 63.
// old=self (no bound_ctrl) -> lanes without source self-compare (idempotent).
#define DPP_MOV(v, CTRL, RMASK) \
  ((unsigned)__builtin_amdgcn_update_dpp((int)(v), (int)(v), (CTRL), (RMASK), 0xf, false))

#define R64_STEP(hi, lo, CTRL, RMASK)                                         \
  {                                                                           \
    unsigned hm_ = DPP_MOV(hi, CTRL, RMASK);                                  \
    unsigned lm_ = DPP_MOV(lo, CTRL, RMASK);                                  \
    bool gt_ = (hm_ > (hi)) || (hm_ == (hi) && lm_ > (lo));                   \
    hi = gt_ ? hm_ : (hi); lo = gt_ ? lm_ : (lo);                             \
  }

#define R64_ALL(hi, lo)                                                       \
  R64_STEP(hi, lo, 0x111, 0xf)                                                \
  R64_STEP(hi, lo, 0x112, 0xf)                                                \
  R64_STEP(hi, lo, 0x114, 0xf)                                                \
  R64_STEP(hi, lo, 0x118, 0xf)                                                \
  R64_STEP(hi, lo, 0x142, 0xa)                                                \
  R64_STEP(hi, lo, 0x143, 0xc)

// Deposit a (wave-uniform) value into lane `lsel`'s slot of a per-lane reg:
// one v_cmp + v_cndmask per value. (v_writelane needs SGPR operands; clang
// won't auto-uniformize ctz(ballot) results -- round-12 compile failure.)
#define DEPOSIT(dst, val, lsel) { (dst) = ((int)lane == (int)(lsel)) ? (val) : (dst); }

// ---------------------------------------------------------------------------
// Sort setup kernel 1: Morton cell id per point + per-cell counts (1 blk/batch)
// ---------------------------------------------------------------------------
__global__ void cell_count(const float4* __restrict__ pts,
                           int* __restrict__ codes, int* __restrict__ counts) {
  const int b = blockIdx.x, tid = threadIdx.x;
  __shared__ int cnt[4096];
  for (int k = tid; k < 4096; k += 1024) cnt[k] = 0;
  __syncthreads();
  for (int j = 0; j < 32; ++j) {
    int i = j * 1024 + tid;
    float4 v = pts[(size_t)b * N_PTS + i];
    int cx = min(63, max(0, (int)(v.x * (64.0f / 70.4f))));
    int cy = min(63, max(0, (int)((v.y + 40.0f) * 0.8f)));
    int code = (int)(part1by1((unsigned)cx) | (part1by1((unsigned)cy) << 1));
    codes[(size_t)b * N_PTS + i] = code;
    atomicAdd(&cnt[code], 1);
  }
  __syncthreads();
  for (int k = tid; k < 4096; k += 1024) counts[b * 4096 + k] = cnt[k];
}

// ---------------------------------------------------------------------------
// Sort setup kernel 2: exclusive prefix sum over 4096 cells (1 wave/batch)
// ---------------------------------------------------------------------------
__global__ void cell_scan(const int* __restrict__ counts, int* __restrict__ offs) {
  const int b = blockIdx.x, lane = threadIdx.x;   // 64 threads
  const int* cnt = counts + b * 4096;
  int* off = offs + b * 4096;
  int s = 0;
  for (int k = 0; k < 64; ++k) s += cnt[lane * 64 + k];
  int incl = s;
#pragma unroll
  for (int o = 1; o < 64; o <<= 1) {
    int t = __shfl_up(incl, o);
    if (lane >= o) incl += t;
  }
  int run = incl - s;                              // exclusive base
  for (int k = 0; k < 64; ++k) {
    int id = lane * 64 + k;
    int t = cnt[id];
    off[id] = run;
    run += t;
  }
}

// ---------------------------------------------------------------------------
// Sort setup kernel 3: scatter points into Morton order (+ original indices)
// ---------------------------------------------------------------------------
__global__ void scatter_pts(const float4* __restrict__ pts,
                            const int* __restrict__ codes,
                            int* __restrict__ offs,
                            float4* __restrict__ spts, int* __restrict__ sorig) {
  const int b = blockIdx.x, tid = threadIdx.x;
  for (int j = 0; j < 32; ++j) {
    int i = j * 1024 + tid;
    int code = codes[(size_t)b * N_PTS + i];
    int pos = atomicAdd(&offs[b * 4096 + code], 1);
    spts[(size_t)b * N_PTS + pos] = pts[(size_t)b * N_PTS + i];
    sorig[(size_t)b * N_PTS + pos] = i;
  }
}

// ---------------------------------------------------------------------------
// Sort setup kernel 4: bbox per 64-point chunk (1 wave/chunk)
// ---------------------------------------------------------------------------
__global__ void chunk_bbox(const float4* __restrict__ spts, float* __restrict__ bbox) {
  const int wid = threadIdx.x >> 6, lane = threadIdx.x & 63;
  const int chunk = blockIdx.x * 4 + wid;          // 0..1023
  const int b = chunk >> 9, c = chunk & (N_CHUNK - 1);
  float4 v = spts[(size_t)b * N_PTS + c * 64 + lane];
  float lx = v.x, ly = v.y, lz = v.z, hx = v.x, hy = v.y, hz = v.z;
#pragma unroll
  for (int o = 32; o >= 1; o >>= 1) {
    lx = fminf(lx, __shfl_xor(lx, o)); hx = fmaxf(hx, __shfl_xor(hx, o));
    ly = fminf(ly, __shfl_xor(ly, o)); hy = fmaxf(hy, __shfl_xor(hy, o));
    lz = fminf(lz, __shfl_xor(lz, o)); hz = fmaxf(hz, __shfl_xor(hz, o));
  }
  if (lane == 0) {
    float* bp = bbox + (size_t)chunk * 6;
    bp[0] = lx; bp[1] = ly; bp[2] = lz; bp[3] = hx; bp[4] = hy; bp[5] = hz;
  }
}

// ---------------------------------------------------------------------------
// Pruned FPS, register-key version. One 1024-thread block (16 waves)/batch.
// Chunk ownership INTERLEAVED: wave = c & 15, lane (c>>4) holds the chunk's
// key (d-bits, ~orig) and candidate coords IN REGISTERS. Dirty test is pure
// register math; per-chunk update = one merged 64-bit DPP chain; C1 reduces
// the wave's own 32 register keys (no barrier vs B). 2 barriers/iter, zero
// LDS atomics. Chunk skip provably exact (lb*(1-1e-5) underestimates any
// ref-rounded distance); tie-break == jnp.argmax first-orig-index.
// ---------------------------------------------------------------------------
__global__ void fps_pruned(const float4* __restrict__ pts,
                           const float4* __restrict__ spts,
                           const int* __restrict__ sorig,
                           const float* __restrict__ bbox,
                           float4* __restrict__ kp_xyz) {
  const int b = blockIdx.x;
  const int tid = threadIdx.x;
  const int wid = tid >> 6, lane = tid & 63;     // 16 waves
  const float4* p4o = pts + (size_t)b * N_PTS;
  const float4* sp4 = spts + (size_t)b * N_PTS;
  const int* sog = sorig + (size_t)b * N_PTS;

  __shared__ float d_lds[N_PTS];                 // 131072 B
  __shared__ unsigned long long wkey[16];
  __shared__ float4 wcoord[16];

  for (int i = tid; i < N_PTS; i += 1024) d_lds[i] = 1e10f;

  // lane l<32 owns chunk cown = l*16 + wid; bbox + key in registers.
  const int cown = lane * 16 + wid;
  float bx0 = 0.f, by0 = 0.f, bz0 = 0.f, bx1 = 0.f, by1 = 0.f, bz1 = 0.f;
  if (lane < 32) {
    const float* bp = bbox + (size_t)b * N_CHUNK * 6 + (size_t)cown * 6;
    bx0 = bp[0]; by0 = bp[1]; bz0 = bp[2]; bx1 = bp[3]; by1 = bp[4]; bz1 = bp[5];
  }
  unsigned khi = __float_as_uint(1e10f);   // chunk key hi (d bits)
  unsigned klo = 0xFFFFFFFFu;              // chunk key lo (~orig)
  unsigned kcx = 0u, kcy = 0u, kcz = 0u;   // candidate coords (bits)

  float4 p0 = p4o[0];
  float sx = p0.x, sy = p0.y, sz = p0.z;
  if (tid == 0) kp_xyz[b * N_KP] = make_float4(sx, sy, sz, 0.f);
  __syncthreads();                               // d_lds init visible

#define PROC(lsel, pp, og, dp)                                                \
  {                                                                           \
    const int c_ = (lsel) * 16 + wid;                                         \
    float ss_ = sqd((pp).x, (pp).y, (pp).z, sx, sy, sz);                      \
    float nd_ = fminf((dp), ss_);                                             \
    d_lds[(c_ << 6) + lane] = nd_;                                            \
    unsigned hi_ = __float_as_uint(nd_);        /* nonneg: bit order==ord */  \
    unsigned lo_ = 0xFFFFFFFFu - (unsigned)(og);                              \
    unsigned rh_ = hi_, rl_ = lo_;                                            \
    R64_ALL(rh_, rl_)                                                         \
    unsigned mb_ = (unsigned)__builtin_amdgcn_readlane((int)rh_, 63);         \
    unsigned cn_ = (unsigned)__builtin_amdgcn_readlane((int)rl_, 63);         \
    unsigned long long cm_ = __ballot(lo_ == cn_);       /* unique lane */    \
    int cl_ = (int)__builtin_ctzll(cm_);                                      \
    unsigned xb_ = (unsigned)__builtin_amdgcn_readlane((int)__float_as_uint((pp).x), cl_); \
    unsigned yb_ = (unsigned)__builtin_amdgcn_readlane((int)__float_as_uint((pp).y), cl_); \
    unsigned zb_ = (unsigned)__builtin_amdgcn_readlane((int)__float_as_uint((pp).z), cl_); \
    DEPOSIT(khi, mb_, (lsel))                                                 \
    DEPOSIT(klo, cn_, (lsel))                                                 \
    DEPOSIT(kcx, xb_, (lsel))                                                 \
    DEPOSIT(kcy, yb_, (lsel))                                                 \
    DEPOSIT(kcz, zb_, (lsel))                                                 \
  }

  for (int it = 1; it < N_KP; ++it) {
    // ---- B': register dirty test + process owned dirty chunks ----
    bool dirty = false;
    if (lane < 32) {
      float dxm = fmaxf(fmaxf(bx0 - sx, sx - bx1), 0.f);
      float dym = fmaxf(fmaxf(by0 - sy, sy - by1), 0.f);
      float dzm = fmaxf(fmaxf(bz0 - sz, sz - bz1), 0.f);
      float lb = (dxm * dxm + dym * dym) + dzm * dzm;
      dirty = lb * 0.99999f < __uint_as_float(khi);
    }
    unsigned mask = (unsigned)(__ballot(dirty) & 0xFFFFFFFFull);
    // 2-deep rotated pipeline over set bits (all control wave-uniform)
    {
      int lA = 0, lB = 0; bool hasA = false, hasB = false;
      float4 pA, pB; int ogA = 0, ogB = 0; float dpA = 0.f, dpB = 0.f;
      if (mask) {
        lA = (int)__builtin_ctz(mask); mask &= mask - 1; hasA = true;
        int i = ((lA * 16 + wid) << 6) + lane;
        pA = sp4[i]; ogA = sog[i]; dpA = d_lds[i];
      }
      if (mask) {
        lB = (int)__builtin_ctz(mask); mask &= mask - 1; hasB = true;
        int i = ((lB * 16 + wid) << 6) + lane;
        pB = sp4[i]; ogB = sog[i]; dpB = d_lds[i];
      }
      while (hasA) {
        PROC(lA, pA, ogA, dpA);
        lA = lB; pA = pB; ogA = ogB; dpA = dpB; hasA = hasB;
        if (mask) {
          lB = (int)__builtin_ctz(mask); mask &= mask - 1; hasB = true;
          int i = ((lB * 16 + wid) << 6) + lane;
          pB = sp4[i]; ogB = sog[i]; dpB = d_lds[i];
        } else hasB = false;
      }
    }
    // ---- C1: wave-internal argmax over own 32 register keys ----
    {
      unsigned hi = (lane < 32) ? khi : 0u;    // neutral (0,0) never wins
      unsigned lo = (lane < 32) ? klo : 0u;
      R64_ALL(hi, lo)
      unsigned mb = (unsigned)__builtin_amdgcn_readlane((int)hi, 63);
      unsigned cn = (unsigned)__builtin_amdgcn_readlane((int)lo, 63);
      unsigned long long cm = __ballot(lane < 32 && khi == mb && klo == cn);
      int cl = (int)__builtin_ctzll(cm);       // unique (og unique per chunk)
      unsigned xb = (unsigned)__builtin_amdgcn_readlane((int)kcx, cl);
      unsigned yb = (unsigned)__builtin_amdgcn_readlane((int)kcy, cl);
      unsigned zb = (unsigned)__builtin_amdgcn_readlane((int)kcz, cl);
      if (lane == 0) {
        wkey[wid] = ((unsigned long long)mb << 32) | cn;
        wcoord[wid] = make_float4(__uint_as_float(xb), __uint_as_float(yb),
                                  __uint_as_float(zb), 0.f);
      }
    }
    __syncthreads();                           // (1) wkey/wcoord visible
    // ---- C2: all threads redundantly pick winner; seed -> registers ----
    unsigned long long kb = wkey[0];
    int wv = 0;
#pragma unroll
    for (int w = 1; w < 16; ++w) {
      unsigned long long t = wkey[w];
      if (t > kb) { kb = t; wv = w; }
    }
    float4 wc = wcoord[wv];
    sx = wc.x; sy = wc.y; sz = wc.z;
    if (tid == 0) kp_xyz[b * N_KP + it] = make_float4(sx, sy, sz, 0.f);
    __syncthreads();                           // (2) reads done before next C1 writes
  }
#undef PROC
}

// ---------------------------------------------------------------------------
// BEV bilinear interpolation -> feat columns [0,256)
// ---------------------------------------------------------------------------
__global__ void bev_kernel(const float4* __restrict__ kp,
                           const float* __restrict__ bev,
                           const int* __restrict__ stride_p,
                           float* __restrict__ feat) {
  const int kpi = blockIdx.x;        // 0..4095
  const int c = threadIdx.x;         // 0..255
  const int b = kpi >> 11;
  float4 k = kp[kpi];
  float sf = (float)stride_p[0];
  float xi = (k.x - 0.0f) / 0.05f / sf;
  float yi = (k.y - (-40.0f)) / 0.05f / sf;
  int fx = (int)floorf(xi), fy = (int)floorf(yi);
  int x0 = min(max(fx, 0), W_BEV - 1), x1 = min(max(fx + 1, 0), W_BEV - 1);
  int y0 = min(max(fy, 0), H_BEV - 1), y1 = min(max(fy + 1, 0), H_BEV - 1);
  float x0f = (float)x0, x1f = (float)x1, y0f = (float)y0, y1f = (float)y1;
  float wa = (x1f - xi) * (y1f - yi);
  float wb = (x1f - xi) * (yi - y0f);
  float wc = (xi - x0f) * (y1f - yi);
  float wd = (xi - x0f) * (yi - y0f);
  const float* fb = bev + (size_t)b * C_BEV * (H_BEV * W_BEV) + (size_t)c * (H_BEV * W_BEV);
  float Ia = fb[y0 * W_BEV + x0], Ib = fb[y1 * W_BEV + x0];
  float Ic = fb[y0 * W_BEV + x1], Id = fb[y1 * W_BEV + x1];
  feat[(size_t)kpi * FEAT_DIM + c] = ((Ia * wa + Ib * wb) + Ic * wc) + Id * wd;
}

__device__ __forceinline__ int sel4(int q, int a, int b, int c, int d) {
  return q == 0 ? a : (q == 1 ? b : (q == 2 ? c : d));
}

// ---------------------------------------------------------------------------
// Ball query: one wave handles 4 keypoints, scans all 32768 points in index
// order, keeps first 16 in-radius indices for both radii.
// ---------------------------------------------------------------------------
__global__ void ballq_kernel(const float4* __restrict__ pts,
                             const float4* __restrict__ kp,
                             int* __restrict__ lists,
                             int* __restrict__ cnts) {
  const int w = threadIdx.x >> 6;
  const int lane = threadIdx.x & 63;
  const int kpbase = blockIdx.x * 16 + w * 4;
  const int b = blockIdx.x >> 7;                 // 128 blocks per batch
  const float4* p4 = pts + (size_t)b * N_PTS;
  __shared__ int l0[4][4][16];
  __shared__ int l1[4][4][16];
  float kx[4], ky[4], kz[4];
  int c0[4] = {0, 0, 0, 0}, c1[4] = {0, 0, 0, 0};
#pragma unroll
  for (int q = 0; q < 4; ++q) {
    float4 kq = kp[kpbase + q];
    kx[q] = kq.x; ky[q] = kq.y; kz[q] = kq.z;
  }
  const float R0SQ = (float)(0.4 * 0.4);
  const float R1SQ = (float)(0.8 * 0.8);
  const unsigned long long below = (lane == 0) ? 0ull : ((~0ull) >> (64 - lane));

  for (int r = 0; r < N_PTS / 64; ++r) {
    const int i = r * 64 + lane;
    float4 v = p4[i];
#pragma unroll
    for (int q = 0; q < 4; ++q) {
      float dd = sqd(v.x, v.y, v.z, kx[q], ky[q], kz[q]);
      bool in1 = dd < R1SQ;
      unsigned long long m1 = __ballot(in1);
      if (m1) {
        bool in0 = dd < R0SQ;
        unsigned long long m0 = __ballot(in0);
        if (c0[q] < 16) {
          if (in0) { int pos = c0[q] + __popcll(m0 & below); if (pos < 16) l0[w][q][pos] = i; }
          c0[q] += __popcll(m0);
        }
        if (c1[q] < 16) {
          if (in1) { int pos = c1[q] + __popcll(m1 & below); if (pos < 16) l1[w][q][pos] = i; }
          c1[q] += __popcll(m1);
        }
      }
    }
  }
  int q = lane >> 4, s = lane & 15;
  int kpi = kpbase + q;
  int cA = sel4(q, min(c0[0], 16), min(c0[1], 16), min(c0[2], 16), min(c0[3], 16));
  int cB = sel4(q, min(c1[0], 16), min(c1[1], 16), min(c1[2], 16), min(c1[3], 16));
  int vA = (s < cA) ? l0[w][q][s] : (cA > 0 ? l0[w][q][0] : 0);
  int vB = (s < cB) ? l1[w][q][s] : (cB > 0 ? l1[w][q][0] : 0);
  lists[(size_t)(0 * M_ROWS + kpi) * 16 + s] = vA;
  lists[(size_t)(1 * M_ROWS + kpi) * 16 + s] = vB;
  if (lane < 4) {
    cnts[0 * M_ROWS + kpbase + lane] = sel4(lane, min(c0[0], 16), min(c0[1], 16), min(c0[2], 16), min(c0[3], 16));
    cnts[1 * M_ROWS + kpbase + lane] = sel4(lane, min(c1[0], 16), min(c1[1], 16), min(c1[2], 16), min(c1[3], 16));
  }
}

// ---------------------------------------------------------------------------
// Gather grouped points, build h=[rel_xyz, w], first matmul (4 -> 16)
// ---------------------------------------------------------------------------
__global__ void group_mlp1(const float4* __restrict__ pts,
                           const float4* __restrict__ kp,
                           const int* __restrict__ lists,
                           const int* __restrict__ cnts,
                           const float* __restrict__ w00,
                           const float* __restrict__ w10,
                           float* __restrict__ abuf) {
  int gid = blockIdx.x * 256 + threadIdx.x;  // 0..131071
  int br = gid >> 16;
  int rem = gid & 65535;
  int bkp = rem >> 4, s = rem & 15;
  int b = bkp >> 11;
  __shared__ float wl[64];
  if (threadIdx.x < 64) wl[threadIdx.x] = (br ? w10 : w00)[threadIdx.x];
  __syncthreads();
  int cnt = cnts[br * M_ROWS + bkp];
  float h0 = 0.f, h1 = 0.f, h2 = 0.f, h3 = 0.f;
  if (cnt > 0) {
    int pidx = lists[(size_t)(br * M_ROWS + bkp) * 16 + s];
    float4 p = pts[(size_t)b * N_PTS + pidx];
    float4 k = kp[bkp];
    h0 = p.x - k.x; h1 = p.y - k.y; h2 = p.z - k.z; h3 = p.w;
  }
  float* out = abuf + (size_t)gid * 16;
#pragma unroll
  for (int c = 0; c < 16; ++c)
    out[c] = ((h0 * wl[c] + h1 * wl[16 + c]) + h2 * wl[32 + c]) + h3 * wl[48 + c];
}

// ---------------------------------------------------------------------------
// Column stats (C=16), per branch: partial sums then final mean/istd
// ---------------------------------------------------------------------------
__global__ void stats16_partial(const float* __restrict__ a, float* __restrict__ part) {
  int br = blockIdx.y, bl = blockIdx.x, t = threadIdx.x;
  const float* base = a + (size_t)br * 65536 * 16;
  float s[16], q[16];
#pragma unroll
  for (int c = 0; c < 16; ++c) { s[c] = 0.f; q[c] = 0.f; }
  for (int rr = 0; rr < 4; ++rr) {
    int row = bl * 1024 + rr * 256 + t;
#pragma unroll
    for (int c = 0; c < 16; ++c) {
      float v = base[(size_t)row * 16 + c];
      s[c] += v; q[c] += v * v;
    }
  }
  __shared__ float sbs[256][16];
  __shared__ float sbq[256][16];
#pragma unroll
  for (int c = 0; c < 16; ++c) { sbs[t][c] = s[c]; sbq[t][c] = q[c]; }
  __syncthreads();
  for (int st = 128; st > 0; st >>= 1) {
    if (t < st) {
#pragma unroll
      for (int c = 0; c < 16; ++c) { sbs[t][c] += sbs[t + st][c]; sbq[t][c] += sbq[t + st][c]; }
    }
    __syncthreads();
  }
  if (t < 16) {
    part[(size_t)(br * 64 + bl) * 32 + t] = sbs[0][t];
    part[(size_t)(br * 64 + bl) * 32 + 16 + t] = sbq[0][t];
  }
}

__global__ void stats16_final(const float* __restrict__ part, float* __restrict__ stats) {
  int t = threadIdx.x;
  if (t < 32) {
    int br = t >> 4, c = t & 15;
    float s = 0.f, q = 0.f;
    for (int bl = 0; bl < 64; ++bl) {
      s += part[(size_t)(br * 64 + bl) * 32 + c];
      q += part[(size_t)(br * 64 + bl) * 32 + 16 + c];
    }
    float m = s / 65536.f;
    float var = q / 65536.f - m * m;
    stats[(br * 16 + c) * 2] = m;
    stats[(br * 16 + c) * 2 + 1] = rsqrtf(var + 1e-5f);
  }
}

// ---------------------------------------------------------------------------
// relu(bn(a1)) @ w_second  (16 -> 16), in-place over abuf
// ---------------------------------------------------------------------------
__global__ void mlp2_kernel(float* __restrict__ abuf, const float* __restrict__ stats,
                            const float* __restrict__ g00, const float* __restrict__ b00,
                            const float* __restrict__ g10, const float* __restrict__ b10,
                            const float* __restrict__ w01, const float* __restrict__ w11) {
  int gid = blockIdx.x * 256 + threadIdx.x;
  int br = gid >> 16;
  __shared__ float wl[256];
  wl[threadIdx.x] = (br ? w11 : w01)[threadIdx.x];
  __syncthreads();
  const float* g = br ? g10 : g00;
  const float* bb = br ? b10 : b00;
  float* row = abuf + (size_t)gid * 16;
  float z[16];
#pragma unroll
  for (int f = 0; f < 16; ++f) {
    float m = stats[(br * 16 + f) * 2], is = stats[(br * 16 + f) * 2 + 1];
    z[f] = fmaxf(0.f, (row[f] - m) * is * g[f] + bb[f]);
  }
  float o[16];
#pragma unroll
  for (int c = 0; c < 16; ++c) o[c] = 0.f;
#pragma unroll
  for (int f = 0; f < 16; ++f) {
#pragma unroll
    for (int c = 0; c < 16; ++c) o[c] += z[f] * wl[f * 16 + c];
  }
#pragma unroll
  for (int c = 0; c < 16; ++c) row[c] = o[c];
}

// ---------------------------------------------------------------------------
// relu(bn(a2)) max-pool over 16 samples -> feat columns [256, 288)
// ---------------------------------------------------------------------------
__global__ void pool_kernel(const float* __restrict__ abuf, const float* __restrict__ stats,
                            const int* __restrict__ cnts,
                            const float* __restrict__ g01, const float* __restrict__ b01,
                            const float* __restrict__ g11, const float* __restrict__ b11,
                            float* __restrict__ feat) {
  int gid = blockIdx.x * 256 + threadIdx.x;   // 131072
  int br = gid >> 16;
  int rem = gid & 65535;
  int bkp = rem >> 4, c = rem & 15;
  const float* g = br ? g11 : g01;
  const float* bb = br ? b11 : b01;
  float m = stats[(br * 16 + c) * 2], is = stats[(br * 16 + c) * 2 + 1];
  float gg = g[c], bv = bb[c];
  const float* base = abuf + ((size_t)br * 65536 + (size_t)bkp * 16) * 16 + c;
  float mx = -1e30f;
#pragma unroll
  for (int s = 0; s < 16; ++s) {
    float v = base[(size_t)s * 16];
    mx = fmaxf(mx, fmaxf(0.f, (v - m) * is * gg + bv));
  }
  if (cnts[br * M_ROWS + bkp] == 0) mx = 0.f;
  feat[(size_t)bkp * FEAT_DIM + 256 + br * 16 + c] = mx;
}

// ---------------------------------------------------------------------------
// Final matmul feat(4096x288) @ wf(288x128)
// ---------------------------------------------------------------------------
__global__ void final_mm(const float* __restrict__ feat, const float* __restrict__ wf,
                         float* __restrict__ hbuf) {
  int row = blockIdx.x;
  int c = threadIdx.x;   // 128
  __shared__ float fr[FEAT_DIM];
  for (int k = c; k < FEAT_DIM; k += 128) fr[k] = feat[(size_t)row * FEAT_DIM + k];
  __syncthreads();
  float acc = 0.f;
#pragma unroll 8
  for (int k = 0; k < FEAT_DIM; ++k) acc += fr[k] * wf[(size_t)k * C_OUT + c];
  hbuf[(size_t)row * C_OUT + c] = acc;
}

__global__ void stats128_partial(const float* __restrict__ hbuf, float* __restrict__ part) {
  int bl = blockIdx.x, c = threadIdx.x;  // 32 blocks x 128 thr
  float s = 0.f, q = 0.f;
  for (int r = 0; r < 128; ++r) {
    float v = hbuf[(size_t)(bl * 128 + r) * C_OUT + c];
    s += v; q += v * v;
  }
  part[(size_t)(bl * 128 + c) * 2] = s;
  part[(size_t)(bl * 128 + c) * 2 + 1] = q;
}

__global__ void stats128_final(const float* __restrict__ part, float* __restrict__ stats) {
  int c = threadIdx.x;  // 128
  float s = 0.f, q = 0.f;
  for (int bl = 0; bl < 32; ++bl) {
    s += part[(size_t)(bl * 128 + c) * 2];
    q += part[(size_t)(bl * 128 + c) * 2 + 1];
  }
  float m = s / 4096.f;
  float var = q / 4096.f - m * m;
  stats[c * 2] = m;
  stats[c * 2 + 1] = rsqrtf(var + 1e-5f);
}

// Output is FLOAT32 (reference returns relu(h) in fp32).
__global__ void out_kernel(const float* __restrict__ hbuf, const float* __restrict__ stats,
                           const float* __restrict__ gf, const float* __restrict__ bf,
                           float* __restrict__ out) {
  int gid = blockIdx.x * 256 + threadIdx.x;  // 524288
  int c = gid & 127;
  float v = hbuf[gid];
  float r = fmaxf(0.f, (v - stats[c * 2]) * stats[c * 2 + 1] * gf[c] + bf[c]);
  out[gid] = r;
}

// ---------------------------------------------------------------------------
extern "C" void kernel_launch(void* const* d_in, const int* in_sizes, int n_in,
                              void* d_out, int out_size, void* d_ws, size_t ws_size,
                              hipStream_t stream) {
  const float4* pts = (const float4*)d_in[0];
  const float* spatial = (const float*)d_in[1];
  const float* w0_0 = (const float*)d_in[2];
  const float* g0_0 = (const float*)d_in[3];
  const float* b0_0 = (const float*)d_in[4];
  const float* w0_1 = (const float*)d_in[5];
  const float* g0_1 = (const float*)d_in[6];
  const float* b0_1 = (const float*)d_in[7];
  const float* w1_0 = (const float*)d_in[8];
  const float* g1_0 = (const float*)d_in[9];
  const float* b1_0 = (const float*)d_in[10];
  const float* w1_1 = (const float*)d_in[11];
  const float* g1_1 = (const float*)d_in[12];
  const float* b1_1 = (const float*)d_in[13];
  const float* wf  = (const float*)d_in[14];
  const float* gf  = (const float*)d_in[15];
  const float* bfp = (const float*)d_in[16];
  const int* stride_p = (const int*)d_in[17];

  char* ws = (char*)d_ws;
  float4* kp_xyz = (float4*)(ws + 0);                 //  65536 B
  int* lists     = (int*)(ws + 65536);                // 524288 B
  int* cnts      = (int*)(ws + 589824);               //  32768 B
  float* abuf    = (float*)(ws + 622592);             // 8388608 B
  float* feat    = (float*)(ws + 9011200);            // 4718592 B
  float* hbuf    = (float*)(ws + 13729792);           // 2097152 B
  float* part16  = (float*)(ws + 15826944);           //  16384 B
  float* stats16 = (float*)(ws + 15843328);           //    256 B
  float* part128 = (float*)(ws + 15843584);           //  32768 B
  float* stats128= (float*)(ws + 15876352);           //   1024 B

  // Sort scratch OVERLAYS abuf (dead until group_mlp1, which runs after fps).
  char* sbase = (char*)abuf;
  float4* spts = (float4*)(sbase + 0);                // 1048576 B
  int* sorig   = (int*)(sbase + 1048576);             //  262144 B
  int* codes   = (int*)(sbase + 1310720);             //  262144 B
  int* counts  = (int*)(sbase + 1572864);             //   32768 B
  int* offs    = (int*)(sbase + 1605632);             //   32768 B
  float* bboxg = (float*)(sbase + 1638400);           //   24576 B

  cell_count<<<B_SZ, 1024, 0, stream>>>(pts, codes, counts);
  cell_scan<<<B_SZ, 64, 0, stream>>>(counts, offs);
  scatter_pts<<<B_SZ, 1024, 0, stream>>>(pts, codes, offs, spts, sorig);
  chunk_bbox<<<256, 256, 0, stream>>>(spts, bboxg);
  fps_pruned<<<B_SZ, 1024, 0, stream>>>(pts, spts, sorig, bboxg, kp_xyz);
  bev_kernel<<<M_ROWS, 256, 0, stream>>>(kp_xyz, spatial, stride_p, feat);
  ballq_kernel<<<256, 256, 0, stream>>>(pts, kp_xyz, lists, cnts);
  group_mlp1<<<512, 256, 0, stream>>>(pts, kp_xyz, lists, cnts, w0_0, w1_0, abuf);
  stats16_partial<<<dim3(64, 2), 256, 0, stream>>>(abuf, part16);
  stats16_final<<<1, 64, 0, stream>>>(part16, stats16);
  mlp2_kernel<<<512, 256, 0, stream>>>(abuf, stats16, g0_0, b0_0, g1_0, b1_0, w0_1, w1_1);
  stats16_partial<<<dim3(64, 2), 256, 0, stream>>>(abuf, part16);
  stats16_final<<<1, 64, 0, stream>>>(part16, stats16);
  pool_kernel<<<512, 256, 0, stream>>>(abuf, stats16, cnts, g0_1, b0_1, g1_1, b1_1, feat);
  final_mm<<<M_ROWS, 128, 0, stream>>>(feat, wf, hbuf);
  stats128_partial<<<32, 128, 0, stream>>>(hbuf, part128);
  stats128_final<<<1, 128, 0, stream>>>(part128, stats128);
  out_kernel<<<2048, 256, 0, stream>>>(hbuf, stats128, gf, bfp, (float*)d_out);
}

// Round 14
// 3731.556 us; speedup vs baseline: 1.3157x; 1.3157x over previous
//
#include <hip/hip_runtime.h>
#include <hip/hip_bf16.h>
#include <limits.h>
#include <cstddef>

// Problem constants
#define B_SZ    2
#define N_PTS   32768
#define N_KP    2048
#define N_CHUNK 512            // 32768 / 64 points per chunk
#define H_BEV   200
#define W_BEV   176
#define C_BEV   256
#define FEAT_DIM 288
#define C_OUT   128
#define M_ROWS  4096           // B_SZ * N_KP

// Exact-rounding squared distance matching numpy: ((dx*dx + dy*dy) + dz*dz),
// adds protected from FMA contraction.
__device__ __forceinline__ float sqd(float ax, float ay, float az,
                                     float bx, float by, float bz) {
  float dx = ax - bx, dy = ay - by, dz = az - bz;
  return __fadd_rn(__fadd_rn(dx * dx, dy * dy), dz * dz);
}

__device__ __forceinline__ unsigned part1by1(unsigned n) {
  n &= 0xFFFF;
  n = (n | (n << 8)) & 0x00FF00FF;
  n = (n | (n << 4)) & 0x0F0F0F0F;
  n = (n | (n << 2)) & 0x33333333;
  n = (n | (n << 1)) & 0x55555555;
  return n;
}

// ---- DPP wave64 reductions (VALU pipe, not ds_bpermute) -------------------
// __builtin_amdgcn_update_dpp needs CONSTANT ctrl/mask args -> macros.
// Sequence: row_shr 1/2/4/8 then row_bcast:15, row_bcast:31; result lands in
// lane 63; readlane broadcasts. old=v (no bound_ctrl) -> lanes without a
// source self-compare -- idempotent for max/min.
#define DPP_MOV(v, CTRL, RMASK) \
  ((unsigned)__builtin_amdgcn_update_dpp((int)(v), (int)(v), (CTRL), (RMASK), 0xf, false))

__device__ __forceinline__ unsigned wave_umax_bcast(unsigned v) {
  unsigned t;
  t = DPP_MOV(v, 0x111, 0xf); v = v > t ? v : t;
  t = DPP_MOV(v, 0x112, 0xf); v = v > t ? v : t;
  t = DPP_MOV(v, 0x114, 0xf); v = v > t ? v : t;
  t = DPP_MOV(v, 0x118, 0xf); v = v > t ? v : t;
  t = DPP_MOV(v, 0x142, 0xa); v = v > t ? v : t;
  t = DPP_MOV(v, 0x143, 0xc); v = v > t ? v : t;
  return (unsigned)__builtin_amdgcn_readlane((int)v, 63);
}
__device__ __forceinline__ unsigned wave_umin_bcast(unsigned v) {
  unsigned t;
  t = DPP_MOV(v, 0x111, 0xf); v = v < t ? v : t;
  t = DPP_MOV(v, 0x112, 0xf); v = v < t ? v : t;
  t = DPP_MOV(v, 0x114, 0xf); v = v < t ? v : t;
  t = DPP_MOV(v, 0x118, 0xf); v = v < t ? v : t;
  t = DPP_MOV(v, 0x142, 0xa); v = v < t ? v : t;
  t = DPP_MOV(v, 0x143, 0xc); v = v < t ? v : t;
  return (unsigned)__builtin_amdgcn_readlane((int)v, 63);
}

// 64-bit lexicographic max reduce steps (used by Phase C)
#define R64_STEP(hi, lo, CTRL, RMASK)                                         \
  {                                                                           \
    unsigned hm_ = DPP_MOV(hi, CTRL, RMASK);                                  \
    unsigned lm_ = DPP_MOV(lo, CTRL, RMASK);                                  \
    bool gt_ = (hm_ > (hi)) || (hm_ == (hi) && lm_ > (lo));                   \
    hi = gt_ ? hm_ : (hi); lo = gt_ ? lm_ : (lo);                             \
  }

#define R64_ALL(hi, lo)                                                       \
  R64_STEP(hi, lo, 0x111, 0xf)                                                \
  R64_STEP(hi, lo, 0x112, 0xf)                                                \
  R64_STEP(hi, lo, 0x114, 0xf)                                                \
  R64_STEP(hi, lo, 0x118, 0xf)                                                \
  R64_STEP(hi, lo, 0x142, 0xa)                                                \
  R64_STEP(hi, lo, 0x143, 0xc)

// ---------------------------------------------------------------------------
// Sort setup kernel 1: Morton cell id per point + per-cell counts (1 blk/batch)
// ---------------------------------------------------------------------------
__global__ void cell_count(const float4* __restrict__ pts,
                           int* __restrict__ codes, int* __restrict__ counts) {
  const int b = blockIdx.x, tid = threadIdx.x;
  __shared__ int cnt[4096];
  for (int k = tid; k < 4096; k += 1024) cnt[k] = 0;
  __syncthreads();
  for (int j = 0; j < 32; ++j) {
    int i = j * 1024 + tid;
    float4 v = pts[(size_t)b * N_PTS + i];
    int cx = min(63, max(0, (int)(v.x * (64.0f / 70.4f))));
    int cy = min(63, max(0, (int)((v.y + 40.0f) * 0.8f)));
    int code = (int)(part1by1((unsigned)cx) | (part1by1((unsigned)cy) << 1));
    codes[(size_t)b * N_PTS + i] = code;
    atomicAdd(&cnt[code], 1);
  }
  __syncthreads();
  for (int k = tid; k < 4096; k += 1024) counts[b * 4096 + k] = cnt[k];
}

// ---------------------------------------------------------------------------
// Sort setup kernel 2: exclusive prefix sum over 4096 cells (1 wave/batch)
// ---------------------------------------------------------------------------
__global__ void cell_scan(const int* __restrict__ counts, int* __restrict__ offs) {
  const int b = blockIdx.x, lane = threadIdx.x;   // 64 threads
  const int* cnt = counts + b * 4096;
  int* off = offs + b * 4096;
  int s = 0;
  for (int k = 0; k < 64; ++k) s += cnt[lane * 64 + k];
  int incl = s;
#pragma unroll
  for (int o = 1; o < 64; o <<= 1) {
    int t = __shfl_up(incl, o);
    if (lane >= o) incl += t;
  }
  int run = incl - s;                              // exclusive base
  for (int k = 0; k < 64; ++k) {
    int id = lane * 64 + k;
    int t = cnt[id];
    off[id] = run;
    run += t;
  }
}

// ---------------------------------------------------------------------------
// Sort setup kernel 3: scatter points into Morton order (+ original indices)
// ---------------------------------------------------------------------------
__global__ void scatter_pts(const float4* __restrict__ pts,
                            const int* __restrict__ codes,
                            int* __restrict__ offs,
                            float4* __restrict__ spts, int* __restrict__ sorig) {
  const int b = blockIdx.x, tid = threadIdx.x;
  for (int j = 0; j < 32; ++j) {
    int i = j * 1024 + tid;
    int code = codes[(size_t)b * N_PTS + i];
    int pos = atomicAdd(&offs[b * 4096 + code], 1);
    spts[(size_t)b * N_PTS + pos] = pts[(size_t)b * N_PTS + i];
    sorig[(size_t)b * N_PTS + pos] = i;
  }
}

// ---------------------------------------------------------------------------
// Sort setup kernel 4: bbox per 64-point chunk (1 wave/chunk)
// ---------------------------------------------------------------------------
__global__ void chunk_bbox(const float4* __restrict__ spts, float* __restrict__ bbox) {
  const int wid = threadIdx.x >> 6, lane = threadIdx.x & 63;
  const int chunk = blockIdx.x * 4 + wid;          // 0..1023
  const int b = chunk >> 9, c = chunk & (N_CHUNK - 1);
  float4 v = spts[(size_t)b * N_PTS + c * 64 + lane];
  float lx = v.x, ly = v.y, lz = v.z, hx = v.x, hy = v.y, hz = v.z;
#pragma unroll
  for (int o = 32; o >= 1; o >>= 1) {
    lx = fminf(lx, __shfl_xor(lx, o)); hx = fmaxf(hx, __shfl_xor(hx, o));
    ly = fminf(ly, __shfl_xor(ly, o)); hy = fmaxf(hy, __shfl_xor(hy, o));
    lz = fminf(lz, __shfl_xor(lz, o)); hz = fmaxf(hz, __shfl_xor(hz, o));
  }
  if (lane == 0) {
    float* bp = bbox + (size_t)chunk * 6;
    bp[0] = lx; bp[1] = ly; bp[2] = lz; bp[3] = hx; bp[4] = hy; bp[5] = hz;
  }
}

// ---------------------------------------------------------------------------
// Pruned FPS. One 1024-thread block per batch. d[] in LDS; per-chunk key =
// (max d, min orig idx among argmax) + candidate coords in LDS. All wave
// reductions on the DPP/VALU pipe. Phase A: ballot-compacted dirty list
// (1 LDS atomic per wave, load-balanced). Phase C: EVERY wave redundantly
// reduces all 512 chunk keys -> no third barrier (round-13 lesson: keep
// PROC lean + list balanced; round-10 lesson: barrier 3 was removable).
// 2 barriers/iter. Chunk skip provably exact; tie-break == jnp.argmax
// first-original-index semantics.
// ---------------------------------------------------------------------------
__global__ void fps_pruned(const float4* __restrict__ pts,
                           const float4* __restrict__ spts,
                           const int* __restrict__ sorig,
                           const float* __restrict__ bbox,
                           float4* __restrict__ kp_xyz) {
  const int b = blockIdx.x;
  const int tid = threadIdx.x;
  const int wid = tid >> 6, lane = tid & 63;
  const float4* p4o = pts + (size_t)b * N_PTS;
  const float4* sp4 = spts + (size_t)b * N_PTS;
  const int* sog = sorig + (size_t)b * N_PTS;
  const unsigned long long below = (lane == 0) ? 0ull : ((~0ull) >> (64 - lane));

  __shared__ float d_lds[N_PTS];          // 131072 B
  __shared__ float keyd[N_CHUNK];         //   2048 B
  __shared__ int keyo[N_CHUNK];           //   2048 B
  __shared__ float keyx[N_CHUNK];         //   2048 B
  __shared__ float keyy[N_CHUNK];         //   2048 B
  __shared__ float keyz[N_CHUNK];         //   2048 B
  __shared__ int dirty_s[2][N_CHUNK];     //   4096 B
  __shared__ int ndirty_s[2];
  // total ~145.4 KB

  for (int i = tid; i < N_PTS; i += 1024) d_lds[i] = 1e10f;
  if (tid < N_CHUNK) keyd[tid] = 1e10f;
  if (tid < 2) ndirty_s[tid] = 0;
  // bbox of the chunk this thread owns -> registers (thread==chunk, fixed)
  float bx0 = 0.f, by0 = 0.f, bz0 = 0.f, bx1 = 0.f, by1 = 0.f, bz1 = 0.f;
  if (tid < N_CHUNK) {
    const float* bp = bbox + (size_t)b * N_CHUNK * 6 + (size_t)tid * 6;
    bx0 = bp[0]; by0 = bp[1]; bz0 = bp[2]; bx1 = bp[3]; by1 = bp[4]; bz1 = bp[5];
  }
  float4 p0 = p4o[0];                     // broadcast load, once
  float sx = p0.x, sy = p0.y, sz = p0.z;
  if (tid == 0) kp_xyz[b * N_KP] = make_float4(sx, sy, sz, 0.f);
  __syncthreads();

#define PROC_CHUNK(cc, pp, og, dp)                                            \
  {                                                                           \
    float ss = sqd((pp).x, (pp).y, (pp).z, sx, sy, sz);                       \
    float nd = fminf((dp), ss);                                               \
    d_lds[((cc) << 6) + lane] = nd;                                           \
    unsigned nb = __float_as_uint(nd);         /* nonneg: bit order==order */ \
    unsigned mb = wave_umax_bcast(nb);                                        \
    unsigned cnd = (nb == mb) ? (unsigned)(og) : 0xFFFFFFFFu;                 \
    cnd = wave_umin_bcast(cnd);                                               \
    if ((unsigned)(og) == cnd) {                                              \
      keyd[cc] = __uint_as_float(mb); keyo[cc] = (int)cnd;                    \
      keyx[cc] = (pp).x; keyy[cc] = (pp).y; keyz[cc] = (pp).z;                \
    }                                                                         \
  }

  for (int it = 1; it < N_KP; ++it) {
    const int s = it & 1;
    // --- Phase A: per-chunk lower-bound test -> ballot-compacted dirty list
    bool dirty = false;
    if (tid < N_CHUNK) {
      float dxm = fmaxf(fmaxf(bx0 - sx, sx - bx1), 0.f);
      float dym = fmaxf(fmaxf(by0 - sy, sy - by1), 0.f);
      float dzm = fmaxf(fmaxf(bz0 - sz, sz - bz1), 0.f);
      float lb = (dxm * dxm + dym * dym) + dzm * dzm;
      dirty = lb * 0.99999f < keyd[tid];
    }
    unsigned long long m = __ballot(dirty);
    if (tid < N_CHUNK) {                    // waves 0-7, whole-wave uniform
      int cw = (int)__popcll(m);
      int base = 0;
      if (lane == 0 && cw) base = atomicAdd(&ndirty_s[s], cw);
      base = __builtin_amdgcn_readfirstlane(base);
      if (dirty) dirty_s[s][base + (int)__popcll(m & below)] = tid;
    }
    if (tid == 1023) ndirty_s[s ^ 1] = 0;   // reset NEXT iter's slot
    __syncthreads();                        // (1)
    const int K = ndirty_s[s];
    // --- Phase B: update dirty chunks; first two rounds' loads pipelined ---
    {
      int cA = (wid < K) ? dirty_s[s][wid] : -1;
      int cB = ((wid + 16) < K) ? dirty_s[s][wid + 16] : -1;
      if (cA >= 0) {                         // wave-uniform branch
        int iA = (cA << 6) + lane;
        float4 pA = sp4[iA];
        int ogA = sog[iA];
        float dpA = d_lds[iA];
        if (cB >= 0) {
          int iB = (cB << 6) + lane;
          float4 pB = sp4[iB];
          int ogB = sog[iB];
          float dpB = d_lds[iB];
          PROC_CHUNK(cA, pA, ogA, dpA);
          PROC_CHUNK(cB, pB, ogB, dpB);
        } else {
          PROC_CHUNK(cA, pA, ogA, dpA);
        }
        for (int r = 2; r * 16 < K; ++r) {
          int ci = r * 16 + wid;
          if (ci < K) {                      // wave-uniform
            int c = dirty_s[s][ci];
            int i2 = (c << 6) + lane;
            float4 p = sp4[i2];
            int og2 = sog[i2];
            float dp2 = d_lds[i2];
            PROC_CHUNK(c, p, og2, dp2);
          }
        }
      }
    }
    __syncthreads();                        // (2) keys final
    // --- Phase C: EVERY wave redundantly reduces all 512 chunk keys ---
    // (keyd/keyo stable until next Phase B, which is behind barrier 1 of the
    //  next iteration -> no barrier needed after this phase.)
    {
      unsigned hi = __float_as_uint(keyd[lane]);
      unsigned lo = 0xFFFFFFFFu - (unsigned)keyo[lane];
      unsigned ch = (unsigned)lane;
#pragma unroll
      for (int j = 1; j < 8; ++j) {
        int c = j * 64 + lane;               // consecutive -> conflict-free
        unsigned h2 = __float_as_uint(keyd[c]);
        unsigned l2 = 0xFFFFFFFFu - (unsigned)keyo[c];
        bool gt = (h2 > hi) || (h2 == hi && l2 > lo);
        hi = gt ? h2 : hi; lo = gt ? l2 : lo; ch = gt ? (unsigned)c : ch;
      }
      unsigned hl = hi, ll = lo;             // save pre-chain local winner
      R64_ALL(hi, lo)
      unsigned mb = (unsigned)__builtin_amdgcn_readlane((int)hi, 63);
      unsigned cn = (unsigned)__builtin_amdgcn_readlane((int)lo, 63);
      // ~orig is globally unique across chunks -> exactly one lane matches
      unsigned long long cm = __ballot(hl == mb && ll == cn);
      int cl = (int)__builtin_ctzll(cm);
      int cb = (int)(unsigned)__builtin_amdgcn_readlane((int)ch, cl);
      sx = keyx[cb]; sy = keyy[cb]; sz = keyz[cb];   // LDS broadcast reads
      if (tid == 0) kp_xyz[b * N_KP + it] = make_float4(sx, sy, sz, 0.f);
    }
  }
#undef PROC_CHUNK
}

// ---------------------------------------------------------------------------
// BEV bilinear interpolation -> feat columns [0,256)
// ---------------------------------------------------------------------------
__global__ void bev_kernel(const float4* __restrict__ kp,
                           const float* __restrict__ bev,
                           const int* __restrict__ stride_p,
                           float* __restrict__ feat) {
  const int kpi = blockIdx.x;        // 0..4095
  const int c = threadIdx.x;         // 0..255
  const int b = kpi >> 11;
  float4 k = kp[kpi];
  float sf = (float)stride_p[0];
  float xi = (k.x - 0.0f) / 0.05f / sf;
  float yi = (k.y - (-40.0f)) / 0.05f / sf;
  int fx = (int)floorf(xi), fy = (int)floorf(yi);
  int x0 = min(max(fx, 0), W_BEV - 1), x1 = min(max(fx + 1, 0), W_BEV - 1);
  int y0 = min(max(fy, 0), H_BEV - 1), y1 = min(max(fy + 1, 0), H_BEV - 1);
  float x0f = (float)x0, x1f = (float)x1, y0f = (float)y0, y1f = (float)y1;
  float wa = (x1f - xi) * (y1f - yi);
  float wb = (x1f - xi) * (yi - y0f);
  float wc = (xi - x0f) * (y1f - yi);
  float wd = (xi - x0f) * (yi - y0f);
  const float* fb = bev + (size_t)b * C_BEV * (H_BEV * W_BEV) + (size_t)c * (H_BEV * W_BEV);
  float Ia = fb[y0 * W_BEV + x0], Ib = fb[y1 * W_BEV + x0];
  float Ic = fb[y0 * W_BEV + x1], Id = fb[y1 * W_BEV + x1];
  feat[(size_t)kpi * FEAT_DIM + c] = ((Ia * wa + Ib * wb) + Ic * wc) + Id * wd;
}

__device__ __forceinline__ int sel4(int q, int a, int b, int c, int d) {
  return q == 0 ? a : (q == 1 ? b : (q == 2 ? c : d));
}

// ---------------------------------------------------------------------------
// Ball query: one wave handles 4 keypoints, scans all 32768 points in index
// order, keeps first 16 in-radius indices for both radii.
// ---------------------------------------------------------------------------
__global__ void ballq_kernel(const float4* __restrict__ pts,
                             const float4* __restrict__ kp,
                             int* __restrict__ lists,
                             int* __restrict__ cnts) {
  const int w = threadIdx.x >> 6;
  const int lane = threadIdx.x & 63;
  const int kpbase = blockIdx.x * 16 + w * 4;
  const int b = blockIdx.x >> 7;                 // 128 blocks per batch
  const float4* p4 = pts + (size_t)b * N_PTS;
  __shared__ int l0[4][4][16];
  __shared__ int l1[4][4][16];
  float kx[4], ky[4], kz[4];
  int c0[4] = {0, 0, 0, 0}, c1[4] = {0, 0, 0, 0};
#pragma unroll
  for (int q = 0; q < 4; ++q) {
    float4 kq = kp[kpbase + q];
    kx[q] = kq.x; ky[q] = kq.y; kz[q] = kq.z;
  }
  const float R0SQ = (float)(0.4 * 0.4);
  const float R1SQ = (float)(0.8 * 0.8);
  const unsigned long long below = (lane == 0) ? 0ull : ((~0ull) >> (64 - lane));

  for (int r = 0; r < N_PTS / 64; ++r) {
    const int i = r * 64 + lane;
    float4 v = p4[i];
#pragma unroll
    for (int q = 0; q < 4; ++q) {
      float dd = sqd(v.x, v.y, v.z, kx[q], ky[q], kz[q]);
      bool in1 = dd < R1SQ;
      unsigned long long m1 = __ballot(in1);
      if (m1) {
        bool in0 = dd < R0SQ;
        unsigned long long m0 = __ballot(in0);
        if (c0[q] < 16) {
          if (in0) { int pos = c0[q] + __popcll(m0 & below); if (pos < 16) l0[w][q][pos] = i; }
          c0[q] += __popcll(m0);
        }
        if (c1[q] < 16) {
          if (in1) { int pos = c1[q] + __popcll(m1 & below); if (pos < 16) l1[w][q][pos] = i; }
          c1[q] += __popcll(m1);
        }
      }
    }
  }
  int q = lane >> 4, s = lane & 15;
  int kpi = kpbase + q;
  int cA = sel4(q, min(c0[0], 16), min(c0[1], 16), min(c0[2], 16), min(c0[3], 16));
  int cB = sel4(q, min(c1[0], 16), min(c1[1], 16), min(c1[2], 16), min(c1[3], 16));
  int vA = (s < cA) ? l0[w][q][s] : (cA > 0 ? l0[w][q][0] : 0);
  int vB = (s < cB) ? l1[w][q][s] : (cB > 0 ? l1[w][q][0] : 0);
  lists[(size_t)(0 * M_ROWS + kpi) * 16 + s] = vA;
  lists[(size_t)(1 * M_ROWS + kpi) * 16 + s] = vB;
  if (lane < 4) {
    cnts[0 * M_ROWS + kpbase + lane] = sel4(lane, min(c0[0], 16), min(c0[1], 16), min(c0[2], 16), min(c0[3], 16));
    cnts[1 * M_ROWS + kpbase + lane] = sel4(lane, min(c1[0], 16), min(c1[1], 16), min(c1[2], 16), min(c1[3], 16));
  }
}

// ---------------------------------------------------------------------------
// Gather grouped points, build h=[rel_xyz, w], first matmul (4 -> 16)
// ---------------------------------------------------------------------------
__global__ void group_mlp1(const float4* __restrict__ pts,
                           const float4* __restrict__ kp,
                           const int* __restrict__ lists,
                           const int* __restrict__ cnts,
                           const float* __restrict__ w00,
                           const float* __restrict__ w10,
                           float* __restrict__ abuf) {
  int gid = blockIdx.x * 256 + threadIdx.x;  // 0..131071
  int br = gid >> 16;
  int rem = gid & 65535;
  int bkp = rem >> 4, s = rem & 15;
  int b = bkp >> 11;
  __shared__ float wl[64];
  if (threadIdx.x < 64) wl[threadIdx.x] = (br ? w10 : w00)[threadIdx.x];
  __syncthreads();
  int cnt = cnts[br * M_ROWS + bkp];
  float h0 = 0.f, h1 = 0.f, h2 = 0.f, h3 = 0.f;
  if (cnt > 0) {
    int pidx = lists[(size_t)(br * M_ROWS + bkp) * 16 + s];
    float4 p = pts[(size_t)b * N_PTS + pidx];
    float4 k = kp[bkp];
    h0 = p.x - k.x; h1 = p.y - k.y; h2 = p.z - k.z; h3 = p.w;
  }
  float* out = abuf + (size_t)gid * 16;
#pragma unroll
  for (int c = 0; c < 16; ++c)
    out[c] = ((h0 * wl[c] + h1 * wl[16 + c]) + h2 * wl[32 + c]) + h3 * wl[48 + c];
}

// ---------------------------------------------------------------------------
// Column stats (C=16), per branch: partial sums then final mean/istd
// ---------------------------------------------------------------------------
__global__ void stats16_partial(const float* __restrict__ a, float* __restrict__ part) {
  int br = blockIdx.y, bl = blockIdx.x, t = threadIdx.x;
  const float* base = a + (size_t)br * 65536 * 16;
  float s[16], q[16];
#pragma unroll
  for (int c = 0; c < 16; ++c) { s[c] = 0.f; q[c] = 0.f; }
  for (int rr = 0; rr < 4; ++rr) {
    int row = bl * 1024 + rr * 256 + t;
#pragma unroll
    for (int c = 0; c < 16; ++c) {
      float v = base[(size_t)row * 16 + c];
      s[c] += v; q[c] += v * v;
    }
  }
  __shared__ float sbs[256][16];
  __shared__ float sbq[256][16];
#pragma unroll
  for (int c = 0; c < 16; ++c) { sbs[t][c] = s[c]; sbq[t][c] = q[c]; }
  __syncthreads();
  for (int st = 128; st > 0; st >>= 1) {
    if (t < st) {
#pragma unroll
      for (int c = 0; c < 16; ++c) { sbs[t][c] += sbs[t + st][c]; sbq[t][c] += sbq[t + st][c]; }
    }
    __syncthreads();
  }
  if (t < 16) {
    part[(size_t)(br * 64 + bl) * 32 + t] = sbs[0][t];
    part[(size_t)(br * 64 + bl) * 32 + 16 + t] = sbq[0][t];
  }
}

__global__ void stats16_final(const float* __restrict__ part, float* __restrict__ stats) {
  int t = threadIdx.x;
  if (t < 32) {
    int br = t >> 4, c = t & 15;
    float s = 0.f, q = 0.f;
    for (int bl = 0; bl < 64; ++bl) {
      s += part[(size_t)(br * 64 + bl) * 32 + c];
      q += part[(size_t)(br * 64 + bl) * 32 + 16 + c];
    }
    float m = s / 65536.f;
    float var = q / 65536.f - m * m;
    stats[(br * 16 + c) * 2] = m;
    stats[(br * 16 + c) * 2 + 1] = rsqrtf(var + 1e-5f);
  }
}

// ---------------------------------------------------------------------------
// relu(bn(a1)) @ w_second  (16 -> 16), in-place over abuf
// ---------------------------------------------------------------------------
__global__ void mlp2_kernel(float* __restrict__ abuf, const float* __restrict__ stats,
                            const float* __restrict__ g00, const float* __restrict__ b00,
                            const float* __restrict__ g10, const float* __restrict__ b10,
                            const float* __restrict__ w01, const float* __restrict__ w11) {
  int gid = blockIdx.x * 256 + threadIdx.x;
  int br = gid >> 16;
  __shared__ float wl[256];
  wl[threadIdx.x] = (br ? w11 : w01)[threadIdx.x];
  __syncthreads();
  const float* g = br ? g10 : g00;
  const float* bb = br ? b10 : b00;
  float* row = abuf + (size_t)gid * 16;
  float z[16];
#pragma unroll
  for (int f = 0; f < 16; ++f) {
    float m = stats[(br * 16 + f) * 2], is = stats[(br * 16 + f) * 2 + 1];
    z[f] = fmaxf(0.f, (row[f] - m) * is * g[f] + bb[f]);
  }
  float o[16];
#pragma unroll
  for (int c = 0; c < 16; ++c) o[c] = 0.f;
#pragma unroll
  for (int f = 0; f < 16; ++f) {
#pragma unroll
    for (int c = 0; c < 16; ++c) o[c] += z[f] * wl[f * 16 + c];
  }
#pragma unroll
  for (int c = 0; c < 16; ++c) row[c] = o[c];
}

// ---------------------------------------------------------------------------
// relu(bn(a2)) max-pool over 16 samples -> feat columns [256, 288)
// ---------------------------------------------------------------------------
__global__ void pool_kernel(const float* __restrict__ abuf, const float* __restrict__ stats,
                            const int* __restrict__ cnts,
                            const float* __restrict__ g01, const float* __restrict__ b01,
                            const float* __restrict__ g11, const float* __restrict__ b11,
                            float* __restrict__ feat) {
  int gid = blockIdx.x * 256 + threadIdx.x;   // 131072
  int br = gid >> 16;
  int rem = gid & 65535;
  int bkp = rem >> 4, c = rem & 15;
  const float* g = br ? g11 : g01;
  const float* bb = br ? b11 : b01;
  float m = stats[(br * 16 + c) * 2], is = stats[(br * 16 + c) * 2 + 1];
  float gg = g[c], bv = bb[c];
  const float* base = abuf + ((size_t)br * 65536 + (size_t)bkp * 16) * 16 + c;
  float mx = -1e30f;
#pragma unroll
  for (int s = 0; s < 16; ++s) {
    float v = base[(size_t)s * 16];
    mx = fmaxf(mx, fmaxf(0.f, (v - m) * is * gg + bv));
  }
  if (cnts[br * M_ROWS + bkp] == 0) mx = 0.f;
  feat[(size_t)bkp * FEAT_DIM + 256 + br * 16 + c] = mx;
}

// ---------------------------------------------------------------------------
// Final matmul feat(4096x288) @ wf(288x128)
// ---------------------------------------------------------------------------
__global__ void final_mm(const float* __restrict__ feat, const float* __restrict__ wf,
                         float* __restrict__ hbuf) {
  int row = blockIdx.x;
  int c = threadIdx.x;   // 128
  __shared__ float fr[FEAT_DIM];
  for (int k = c; k < FEAT_DIM; k += 128) fr[k] = feat[(size_t)row * FEAT_DIM + k];
  __syncthreads();
  float acc = 0.f;
#pragma unroll 8
  for (int k = 0; k < FEAT_DIM; ++k) acc += fr[k] * wf[(size_t)k * C_OUT + c];
  hbuf[(size_t)row * C_OUT + c] = acc;
}

__global__ void stats128_partial(const float* __restrict__ hbuf, float* __restrict__ part) {
  int bl = blockIdx.x, c = threadIdx.x;  // 32 blocks x 128 thr
  float s = 0.f, q = 0.f;
  for (int r = 0; r < 128; ++r) {
    float v = hbuf[(size_t)(bl * 128 + r) * C_OUT + c];
    s += v; q += v * v;
  }
  part[(size_t)(bl * 128 + c) * 2] = s;
  part[(size_t)(bl * 128 + c) * 2 + 1] = q;
}

__global__ void stats128_final(const float* __restrict__ part, float* __restrict__ stats) {
  int c = threadIdx.x;  // 128
  float s = 0.f, q = 0.f;
  for (int bl = 0; bl < 32; ++bl) {
    s += part[(size_t)(bl * 128 + c) * 2];
    q += part[(size_t)(bl * 128 + c) * 2 + 1];
  }
  float m = s / 4096.f;
  float var = q / 4096.f - m * m;
  stats[c * 2] = m;
  stats[c * 2 + 1] = rsqrtf(var + 1e-5f);
}

// Output is FLOAT32 (reference returns relu(h) in fp32).
__global__ void out_kernel(const float* __restrict__ hbuf, const float* __restrict__ stats,
                           const float* __restrict__ gf, const float* __restrict__ bf,
                           float* __restrict__ out) {
  int gid = blockIdx.x * 256 + threadIdx.x;  // 524288
  int c = gid & 127;
  float v = hbuf[gid];
  float r = fmaxf(0.f, (v - stats[c * 2]) * stats[c * 2 + 1] * gf[c] + bf[c]);
  out[gid] = r;
}

// ---------------------------------------------------------------------------
extern "C" void kernel_launch(void* const* d_in, const int* in_sizes, int n_in,
                              void* d_out, int out_size, void* d_ws, size_t ws_size,
                              hipStream_t stream) {
  const float4* pts = (const float4*)d_in[0];
  const float* spatial = (const float*)d_in[1];
  const float* w0_0 = (const float*)d_in[2];
  const float* g0_0 = (const float*)d_in[3];
  const float* b0_0 = (const float*)d_in[4];
  const float* w0_1 = (const float*)d_in[5];
  const float* g0_1 = (const float*)d_in[6];
  const float* b0_1 = (const float*)d_in[7];
  const float* w1_0 = (const float*)d_in[8];
  const float* g1_0 = (const float*)d_in[9];
  const float* b1_0 = (const float*)d_in[10];
  const float* w1_1 = (const float*)d_in[11];
  const float* g1_1 = (const float*)d_in[12];
  const float* b1_1 = (const float*)d_in[13];
  const float* wf  = (const float*)d_in[14];
  const float* gf  = (const float*)d_in[15];
  const float* bfp = (const float*)d_in[16];
  const int* stride_p = (const int*)d_in[17];

  char* ws = (char*)d_ws;
  float4* kp_xyz = (float4*)(ws + 0);                 //  65536 B
  int* lists     = (int*)(ws + 65536);                // 524288 B
  int* cnts      = (int*)(ws + 589824);               //  32768 B
  float* abuf    = (float*)(ws + 622592);             // 8388608 B
  float* feat    = (float*)(ws + 9011200);            // 4718592 B
  float* hbuf    = (float*)(ws + 13729792);           // 2097152 B
  float* part16  = (float*)(ws + 15826944);           //  16384 B
  float* stats16 = (float*)(ws + 15843328);           //    256 B
  float* part128 = (float*)(ws + 15843584);           //  32768 B
  float* stats128= (float*)(ws + 15876352);           //   1024 B

  // Sort scratch OVERLAYS abuf (dead until group_mlp1, which runs after fps).
  char* sbase = (char*)abuf;
  float4* spts = (float4*)(sbase + 0);                // 1048576 B
  int* sorig   = (int*)(sbase + 1048576);             //  262144 B
  int* codes   = (int*)(sbase + 1310720);             //  262144 B
  int* counts  = (int*)(sbase + 1572864);             //   32768 B
  int* offs    = (int*)(sbase + 1605632);             //   32768 B
  float* bboxg = (float*)(sbase + 1638400);           //   24576 B

  cell_count<<<B_SZ, 1024, 0, stream>>>(pts, codes, counts);
  cell_scan<<<B_SZ, 64, 0, stream>>>(counts, offs);
  scatter_pts<<<B_SZ, 1024, 0, stream>>>(pts, codes, offs, spts, sorig);
  chunk_bbox<<<256, 256, 0, stream>>>(spts, bboxg);
  fps_pruned<<<B_SZ, 1024, 0, stream>>>(pts, spts, sorig, bboxg, kp_xyz);
  bev_kernel<<<M_ROWS, 256, 0, stream>>>(kp_xyz, spatial, stride_p, feat);
  ballq_kernel<<<256, 256, 0, stream>>>(pts, kp_xyz, lists, cnts);
  group_mlp1<<<512, 256, 0, stream>>>(pts, kp_xyz, lists, cnts, w0_0, w1_0, abuf);
  stats16_partial<<<dim3(64, 2), 256, 0, stream>>>(abuf, part16);
  stats16_final<<<1, 64, 0, stream>>>(part16, stats16);
  mlp2_kernel<<<512, 256, 0, stream>>>(abuf, stats16, g0_0, b0_0, g1_0, b1_0, w0_1, w1_1);
  stats16_partial<<<dim3(64, 2), 256, 0, stream>>>(abuf, part16);
  stats16_final<<<1, 64, 0, stream>>>(part16, stats16);
  pool_kernel<<<512, 256, 0, stream>>>(abuf, stats16, cnts, g0_1, b0_1, g1_1, b1_1, feat);
  final_mm<<<M_ROWS, 128, 0, stream>>>(feat, wf, hbuf);
  stats128_partial<<<32, 128, 0, stream>>>(hbuf, part128);
  stats128_final<<<1, 128, 0, stream>>>(part128, stats128);
  out_kernel<<<2048, 256, 0, stream>>>(hbuf, stats128, gf, bfp, (float*)d_out);
}

// Round 15
// 3333.833 us; speedup vs baseline: 1.4727x; 1.1193x over previous
//
#include <hip/hip_runtime.h>
#include <hip/hip_bf16.h>
#include <limits.h>
#include <cstddef>

// Problem constants
#define B_SZ    2
#define N_PTS   32768
#define N_KP    2048
#define N_CHUNK 512            // 32768 / 64 points per chunk
#define H_BEV   200
#define W_BEV   176
#define C_BEV   256
#define FEAT_DIM 288
#define C_OUT   128
#define M_ROWS  4096           // B_SZ * N_KP

// Exact-rounding squared distance matching numpy: ((dx*dx + dy*dy) + dz*dz),
// adds protected from FMA contraction.
__device__ __forceinline__ float sqd(float ax, float ay, float az,
                                     float bx, float by, float bz) {
  float dx = ax - bx, dy = ay - by, dz = az - bz;
  return __fadd_rn(__fadd_rn(dx * dx, dy * dy), dz * dz);
}

__device__ __forceinline__ unsigned part1by1(unsigned n) {
  n &= 0xFFFF;
  n = (n | (n << 8)) & 0x00FF00FF;
  n = (n | (n << 4)) & 0x0F0F0F0F;
  n = (n | (n << 2)) & 0x33333333;
  n = (n | (n << 1)) & 0x55555555;
  return n;
}

// ---- DPP wave64 reductions (VALU pipe) ------------------------------------
#define DPP_MOV(v, CTRL, RMASK) \
  ((unsigned)__builtin_amdgcn_update_dpp((int)(v), (int)(v), (CTRL), (RMASK), 0xf, false))

__device__ __forceinline__ unsigned wave_umax_bcast(unsigned v) {
  unsigned t;
  t = DPP_MOV(v, 0x111, 0xf); v = v > t ? v : t;
  t = DPP_MOV(v, 0x112, 0xf); v = v > t ? v : t;
  t = DPP_MOV(v, 0x114, 0xf); v = v > t ? v : t;
  t = DPP_MOV(v, 0x118, 0xf); v = v > t ? v : t;
  t = DPP_MOV(v, 0x142, 0xa); v = v > t ? v : t;
  t = DPP_MOV(v, 0x143, 0xc); v = v > t ? v : t;
  return (unsigned)__builtin_amdgcn_readlane((int)v, 63);
}

// 64-bit lexicographic max reduce steps (used by Phase C)
#define R64_STEP(hi, lo, CTRL, RMASK)                                         \
  {                                                                           \
    unsigned hm_ = DPP_MOV(hi, CTRL, RMASK);                                  \
    unsigned lm_ = DPP_MOV(lo, CTRL, RMASK);                                  \
    bool gt_ = (hm_ > (hi)) || (hm_ == (hi) && lm_ > (lo));                   \
    hi = gt_ ? hm_ : (hi); lo = gt_ ? lm_ : (lo);                             \
  }

#define R64_ALL(hi, lo)                                                       \
  R64_STEP(hi, lo, 0x111, 0xf)                                                \
  R64_STEP(hi, lo, 0x112, 0xf)                                                \
  R64_STEP(hi, lo, 0x114, 0xf)                                                \
  R64_STEP(hi, lo, 0x118, 0xf)                                                \
  R64_STEP(hi, lo, 0x142, 0xa)                                                \
  R64_STEP(hi, lo, 0x143, 0xc)

// ---------------------------------------------------------------------------
// Sort setup kernel 1: Morton cell id per point + per-cell counts (1 blk/batch)
// ---------------------------------------------------------------------------
__global__ void cell_count(const float4* __restrict__ pts,
                           int* __restrict__ codes, int* __restrict__ counts) {
  const int b = blockIdx.x, tid = threadIdx.x;
  __shared__ int cnt[4096];
  for (int k = tid; k < 4096; k += 1024) cnt[k] = 0;
  __syncthreads();
  for (int j = 0; j < 32; ++j) {
    int i = j * 1024 + tid;
    float4 v = pts[(size_t)b * N_PTS + i];
    int cx = min(63, max(0, (int)(v.x * (64.0f / 70.4f))));
    int cy = min(63, max(0, (int)((v.y + 40.0f) * 0.8f)));
    int code = (int)(part1by1((unsigned)cx) | (part1by1((unsigned)cy) << 1));
    codes[(size_t)b * N_PTS + i] = code;
    atomicAdd(&cnt[code], 1);
  }
  __syncthreads();
  for (int k = tid; k < 4096; k += 1024) counts[b * 4096 + k] = cnt[k];
}

// ---------------------------------------------------------------------------
// Sort setup kernel 2: exclusive prefix sum over 4096 cells (1 wave/batch)
// ---------------------------------------------------------------------------
__global__ void cell_scan(const int* __restrict__ counts, int* __restrict__ offs) {
  const int b = blockIdx.x, lane = threadIdx.x;   // 64 threads
  const int* cnt = counts + b * 4096;
  int* off = offs + b * 4096;
  int s = 0;
  for (int k = 0; k < 64; ++k) s += cnt[lane * 64 + k];
  int incl = s;
#pragma unroll
  for (int o = 1; o < 64; o <<= 1) {
    int t = __shfl_up(incl, o);
    if (lane >= o) incl += t;
  }
  int run = incl - s;                              // exclusive base
  for (int k = 0; k < 64; ++k) {
    int id = lane * 64 + k;
    int t = cnt[id];
    off[id] = run;
    run += t;
  }
}

// ---------------------------------------------------------------------------
// Sort setup kernel 3: scatter points into Morton order. Original index is
// PACKED into w (bit pattern) -- no separate sorig array.
// ---------------------------------------------------------------------------
__global__ void scatter_pts(const float4* __restrict__ pts,
                            const int* __restrict__ codes,
                            int* __restrict__ offs,
                            float4* __restrict__ spts) {
  const int b = blockIdx.x, tid = threadIdx.x;
  for (int j = 0; j < 32; ++j) {
    int i = j * 1024 + tid;
    int code = codes[(size_t)b * N_PTS + i];
    int pos = atomicAdd(&offs[b * 4096 + code], 1);
    float4 v = pts[(size_t)b * N_PTS + i];
    v.w = __int_as_float(i);
    spts[(size_t)b * N_PTS + pos] = v;
  }
}

// ---------------------------------------------------------------------------
// Sort setup kernel 3.5: in-wave bitonic sort of each 64-point chunk by
// original index (w bits), ascending. Makes within-chunk argmax tie-break a
// simple ctz(ballot) in the FPS hot loop.
// ---------------------------------------------------------------------------
__global__ void chunk_sort(float4* __restrict__ spts) {
  const int wid = threadIdx.x >> 6, lane = threadIdx.x & 63;
  const int chunk = blockIdx.x * 4 + wid;          // 0..1023
  const int b = chunk >> 9, c = chunk & (N_CHUNK - 1);
  float4 v = spts[(size_t)b * N_PTS + c * 64 + lane];
  float x = v.x, y = v.y, z = v.z, w = v.w;
  int key = __float_as_int(w);
#pragma unroll
  for (int k = 2; k <= 64; k <<= 1) {
#pragma unroll
    for (int j = k >> 1; j > 0; j >>= 1) {
      float xx = __shfl_xor(x, j);
      float yy = __shfl_xor(y, j);
      float zz = __shfl_xor(z, j);
      float ww = __shfl_xor(w, j);
      int kk = __float_as_int(ww);
      bool lower = (lane & j) == 0;
      bool up = (lane & k) == 0;
      bool cmp = key > kk;
      bool takeOther = cmp ^ lower ^ up;
      if (takeOther) { x = xx; y = yy; z = zz; w = ww; key = kk; }
    }
  }
  spts[(size_t)b * N_PTS + c * 64 + lane] = make_float4(x, y, z, w);
}

// ---------------------------------------------------------------------------
// Sort setup kernel 4: bbox per 64-point chunk (1 wave/chunk)
// ---------------------------------------------------------------------------
__global__ void chunk_bbox(const float4* __restrict__ spts, float* __restrict__ bbox) {
  const int wid = threadIdx.x >> 6, lane = threadIdx.x & 63;
  const int chunk = blockIdx.x * 4 + wid;          // 0..1023
  const int b = chunk >> 9, c = chunk & (N_CHUNK - 1);
  float4 v = spts[(size_t)b * N_PTS + c * 64 + lane];
  float lx = v.x, ly = v.y, lz = v.z, hx = v.x, hy = v.y, hz = v.z;
#pragma unroll
  for (int o = 32; o >= 1; o >>= 1) {
    lx = fminf(lx, __shfl_xor(lx, o)); hx = fmaxf(hx, __shfl_xor(hx, o));
    ly = fminf(ly, __shfl_xor(ly, o)); hy = fmaxf(hy, __shfl_xor(hy, o));
    lz = fminf(lz, __shfl_xor(lz, o)); hz = fmaxf(hz, __shfl_xor(hz, o));
  }
  if (lane == 0) {
    float* bp = bbox + (size_t)chunk * 6;
    bp[0] = lx; bp[1] = ly; bp[2] = lz; bp[3] = hx; bp[4] = hy; bp[5] = hz;
  }
}

// ---------------------------------------------------------------------------
// Pruned FPS, ownership version. One 512-thread block (8 waves) per batch.
// Wave w owns chunks c == w (mod 8); lane (c>>3) tests chunk c against a
// REGISTER-cached chunk key (kreg). No dirty list, no atomics. Chunks are
// pre-sorted by orig index -> within-chunk min-orig tie-break is
// ctz(ballot(d==max)): PROC has ONE DPP chain. 2 barriers/iter (keys are
// read by all waves in C, written by owners in B). Skip provably exact;
// tie-break == jnp.argmax first-original-index.
// ---------------------------------------------------------------------------
__global__ void fps_pruned(const float4* __restrict__ pts,
                           const float4* __restrict__ spts,
                           const float* __restrict__ bbox,
                           float4* __restrict__ kp_xyz) {
  const int b = blockIdx.x;
  const int tid = threadIdx.x;
  const int wid = tid >> 6, lane = tid & 63;     // 8 waves
  const float4* p4o = pts + (size_t)b * N_PTS;
  const float4* sp4 = spts + (size_t)b * N_PTS;

  __shared__ float d_lds[N_PTS];          // 131072 B
  __shared__ float keyd[N_CHUNK];         //   2048 B
  __shared__ int keyo[N_CHUNK];           //   2048 B
  __shared__ float keyx[N_CHUNK];         //   2048 B
  __shared__ float keyy[N_CHUNK];         //   2048 B
  __shared__ float keyz[N_CHUNK];         //   2048 B
  // total ~141.3 KB

  for (int i = tid; i < N_PTS; i += 512) d_lds[i] = 1e10f;
  if (tid < N_CHUNK) { keyd[tid] = 1e10f; keyo[tid] = 0; keyx[tid] = 0.f; keyy[tid] = 0.f; keyz[tid] = 0.f; }

  // this lane owns chunk cown = lane*8 + wid (all 512 chunks covered)
  const int cown = lane * 8 + wid;
  const float* bp = bbox + (size_t)b * N_CHUNK * 6 + (size_t)cown * 6;
  float bx0 = bp[0], by0 = bp[1], bz0 = bp[2];
  float bx1 = bp[3], by1 = bp[4], bz1 = bp[5];
  float kreg = 1e10f;                      // register mirror of keyd[cown]

  float4 p0 = p4o[0];
  float sx = p0.x, sy = p0.y, sz = p0.z;
  if (tid == 0) kp_xyz[b * N_KP] = make_float4(sx, sy, sz, 0.f);
  __syncthreads();

#define PROC_CHUNK(cc, pp, dp)                                                \
  {                                                                           \
    float ss = sqd((pp).x, (pp).y, (pp).z, sx, sy, sz);                       \
    float nd = fminf((dp), ss);                                               \
    d_lds[((cc) << 6) + lane] = nd;                                           \
    unsigned nb = __float_as_uint(nd);         /* nonneg: bit order==order */ \
    unsigned mb = wave_umax_bcast(nb);                                        \
    unsigned long long win = __ballot(nb == mb);                              \
    int cl = (int)__builtin_ctzll(win);        /* sorted -> min orig lane */  \
    if (lane == ((cc) >> 3)) kreg = __uint_as_float(mb);                      \
    if (lane == cl) {                                                         \
      keyd[cc] = __uint_as_float(mb);                                         \
      keyo[cc] = __float_as_int((pp).w);                                      \
      keyx[cc] = (pp).x; keyy[cc] = (pp).y; keyz[cc] = (pp).z;                \
    }                                                                         \
  }

  for (int it = 1; it < N_KP; ++it) {
    // ---- test + B: register dirty test, process owned dirty chunks ----
    float dxm = fmaxf(fmaxf(bx0 - sx, sx - bx1), 0.f);
    float dym = fmaxf(fmaxf(by0 - sy, sy - by1), 0.f);
    float dzm = fmaxf(fmaxf(bz0 - sz, sz - bz1), 0.f);
    float lb = (dxm * dxm + dym * dym) + dzm * dzm;
    bool dirty = lb * 0.99999f < kreg;
    unsigned long long mask = __ballot(dirty);
    // 2-deep rotated pipeline over set bits (wave-uniform control)
    {
      int cA = 0, cB = 0; bool hasA = false, hasB = false;
      float4 pA, pB; float dpA = 0.f, dpB = 0.f;
      if (mask) {
        int l = (int)__builtin_ctzll(mask); mask &= mask - 1; hasA = true;
        cA = l * 8 + wid;
        int i = (cA << 6) + lane;
        pA = sp4[i]; dpA = d_lds[i];
      }
      if (mask) {
        int l = (int)__builtin_ctzll(mask); mask &= mask - 1; hasB = true;
        cB = l * 8 + wid;
        int i = (cB << 6) + lane;
        pB = sp4[i]; dpB = d_lds[i];
      }
      while (hasA) {
        PROC_CHUNK(cA, pA, dpA);
        cA = cB; pA = pB; dpA = dpB; hasA = hasB;
        if (mask) {
          int l = (int)__builtin_ctzll(mask); mask &= mask - 1; hasB = true;
          cB = l * 8 + wid;
          int i = (cB << 6) + lane;
          pB = sp4[i]; dpB = d_lds[i];
        } else hasB = false;
      }
    }
    __syncthreads();                        // (1) keys final
    // ---- C: every wave redundantly reduces all 512 chunk keys ----
    {
      unsigned hi = __float_as_uint(keyd[lane]);
      unsigned lo = 0xFFFFFFFFu - (unsigned)keyo[lane];
      unsigned ch = (unsigned)lane;
#pragma unroll
      for (int j = 1; j < 8; ++j) {
        int c = j * 64 + lane;               // consecutive -> conflict-free
        unsigned h2 = __float_as_uint(keyd[c]);
        unsigned l2 = 0xFFFFFFFFu - (unsigned)keyo[c];
        bool gt = (h2 > hi) || (h2 == hi && l2 > lo);
        hi = gt ? h2 : hi; lo = gt ? l2 : lo; ch = gt ? (unsigned)c : ch;
      }
      unsigned hl = hi, ll = lo;             // save pre-chain local winner
      R64_ALL(hi, lo)
      unsigned mb = (unsigned)__builtin_amdgcn_readlane((int)hi, 63);
      unsigned cn = (unsigned)__builtin_amdgcn_readlane((int)lo, 63);
      // ~orig globally unique -> exactly one lane matches
      unsigned long long cm = __ballot(hl == mb && ll == cn);
      int cl = (int)__builtin_ctzll(cm);
      int cb = (int)(unsigned)__builtin_amdgcn_readlane((int)ch, cl);
      sx = keyx[cb]; sy = keyy[cb]; sz = keyz[cb];   // LDS broadcast reads
      if (tid == 0) kp_xyz[b * N_KP + it] = make_float4(sx, sy, sz, 0.f);
    }
    __syncthreads();                        // (2) C reads done before next B writes
  }
#undef PROC_CHUNK
}

// ---------------------------------------------------------------------------
// BEV bilinear interpolation -> feat columns [0,256)
// ---------------------------------------------------------------------------
__global__ void bev_kernel(const float4* __restrict__ kp,
                           const float* __restrict__ bev,
                           const int* __restrict__ stride_p,
                           float* __restrict__ feat) {
  const int kpi = blockIdx.x;        // 0..4095
  const int c = threadIdx.x;         // 0..255
  const int b = kpi >> 11;
  float4 k = kp[kpi];
  float sf = (float)stride_p[0];
  float xi = (k.x - 0.0f) / 0.05f / sf;
  float yi = (k.y - (-40.0f)) / 0.05f / sf;
  int fx = (int)floorf(xi), fy = (int)floorf(yi);
  int x0 = min(max(fx, 0), W_BEV - 1), x1 = min(max(fx + 1, 0), W_BEV - 1);
  int y0 = min(max(fy, 0), H_BEV - 1), y1 = min(max(fy + 1, 0), H_BEV - 1);
  float x0f = (float)x0, x1f = (float)x1, y0f = (float)y0, y1f = (float)y1;
  float wa = (x1f - xi) * (y1f - yi);
  float wb = (x1f - xi) * (yi - y0f);
  float wc = (xi - x0f) * (y1f - yi);
  float wd = (xi - x0f) * (yi - y0f);
  const float* fb = bev + (size_t)b * C_BEV * (H_BEV * W_BEV) + (size_t)c * (H_BEV * W_BEV);
  float Ia = fb[y0 * W_BEV + x0], Ib = fb[y1 * W_BEV + x0];
  float Ic = fb[y0 * W_BEV + x1], Id = fb[y1 * W_BEV + x1];
  feat[(size_t)kpi * FEAT_DIM + c] = ((Ia * wa + Ib * wb) + Ic * wc) + Id * wd;
}

__device__ __forceinline__ int sel4(int q, int a, int b, int c, int d) {
  return q == 0 ? a : (q == 1 ? b : (q == 2 ? c : d));
}

// ---------------------------------------------------------------------------
// Ball query: one wave handles 4 keypoints, scans all 32768 points in index
// order, keeps first 16 in-radius indices for both radii.
// ---------------------------------------------------------------------------
__global__ void ballq_kernel(const float4* __restrict__ pts,
                             const float4* __restrict__ kp,
                             int* __restrict__ lists,
                             int* __restrict__ cnts) {
  const int w = threadIdx.x >> 6;
  const int lane = threadIdx.x & 63;
  const int kpbase = blockIdx.x * 16 + w * 4;
  const int b = blockIdx.x >> 7;                 // 128 blocks per batch
  const float4* p4 = pts + (size_t)b * N_PTS;
  __shared__ int l0[4][4][16];
  __shared__ int l1[4][4][16];
  float kx[4], ky[4], kz[4];
  int c0[4] = {0, 0, 0, 0}, c1[4] = {0, 0, 0, 0};
#pragma unroll
  for (int q = 0; q < 4; ++q) {
    float4 kq = kp[kpbase + q];
    kx[q] = kq.x; ky[q] = kq.y; kz[q] = kq.z;
  }
  const float R0SQ = (float)(0.4 * 0.4);
  const float R1SQ = (float)(0.8 * 0.8);
  const unsigned long long below = (lane == 0) ? 0ull : ((~0ull) >> (64 - lane));

  for (int r = 0; r < N_PTS / 64; ++r) {
    const int i = r * 64 + lane;
    float4 v = p4[i];
#pragma unroll
    for (int q = 0; q < 4; ++q) {
      float dd = sqd(v.x, v.y, v.z, kx[q], ky[q], kz[q]);
      bool in1 = dd < R1SQ;
      unsigned long long m1 = __ballot(in1);
      if (m1) {
        bool in0 = dd < R0SQ;
        unsigned long long m0 = __ballot(in0);
        if (c0[q] < 16) {
          if (in0) { int pos = c0[q] + __popcll(m0 & below); if (pos < 16) l0[w][q][pos] = i; }
          c0[q] += __popcll(m0);
        }
        if (c1[q] < 16) {
          if (in1) { int pos = c1[q] + __popcll(m1 & below); if (pos < 16) l1[w][q][pos] = i; }
          c1[q] += __popcll(m1);
        }
      }
    }
  }
  int q = lane >> 4, s = lane & 15;
  int kpi = kpbase + q;
  int cA = sel4(q, min(c0[0], 16), min(c0[1], 16), min(c0[2], 16), min(c0[3], 16));
  int cB = sel4(q, min(c1[0], 16), min(c1[1], 16), min(c1[2], 16), min(c1[3], 16));
  int vA = (s < cA) ? l0[w][q][s] : (cA > 0 ? l0[w][q][0] : 0);
  int vB = (s < cB) ? l1[w][q][s] : (cB > 0 ? l1[w][q][0] : 0);
  lists[(size_t)(0 * M_ROWS + kpi) * 16 + s] = vA;
  lists[(size_t)(1 * M_ROWS + kpi) * 16 + s] = vB;
  if (lane < 4) {
    cnts[0 * M_ROWS + kpbase + lane] = sel4(lane, min(c0[0], 16), min(c0[1], 16), min(c0[2], 16), min(c0[3], 16));
    cnts[1 * M_ROWS + kpbase + lane] = sel4(lane, min(c1[0], 16), min(c1[1], 16), min(c1[2], 16), min(c1[3], 16));
  }
}

// ---------------------------------------------------------------------------
// Gather grouped points, build h=[rel_xyz, w], first matmul (4 -> 16)
// ---------------------------------------------------------------------------
__global__ void group_mlp1(const float4* __restrict__ pts,
                           const float4* __restrict__ kp,
                           const int* __restrict__ lists,
                           const int* __restrict__ cnts,
                           const float* __restrict__ w00,
                           const float* __restrict__ w10,
                           float* __restrict__ abuf) {
  int gid = blockIdx.x * 256 + threadIdx.x;  // 0..131071
  int br = gid >> 16;
  int rem = gid & 65535;
  int bkp = rem >> 4, s = rem & 15;
  int b = bkp >> 11;
  __shared__ float wl[64];
  if (threadIdx.x < 64) wl[threadIdx.x] = (br ? w10 : w00)[threadIdx.x];
  __syncthreads();
  int cnt = cnts[br * M_ROWS + bkp];
  float h0 = 0.f, h1 = 0.f, h2 = 0.f, h3 = 0.f;
  if (cnt > 0) {
    int pidx = lists[(size_t)(br * M_ROWS + bkp) * 16 + s];
    float4 p = pts[(size_t)b * N_PTS + pidx];
    float4 k = kp[bkp];
    h0 = p.x - k.x; h1 = p.y - k.y; h2 = p.z - k.z; h3 = p.w;
  }
  float* out = abuf + (size_t)gid * 16;
#pragma unroll
  for (int c = 0; c < 16; ++c)
    out[c] = ((h0 * wl[c] + h1 * wl[16 + c]) + h2 * wl[32 + c]) + h3 * wl[48 + c];
}

// ---------------------------------------------------------------------------
// Column stats (C=16), per branch: partial sums then final mean/istd
// ---------------------------------------------------------------------------
__global__ void stats16_partial(const float* __restrict__ a, float* __restrict__ part) {
  int br = blockIdx.y, bl = blockIdx.x, t = threadIdx.x;
  const float* base = a + (size_t)br * 65536 * 16;
  float s[16], q[16];
#pragma unroll
  for (int c = 0; c < 16; ++c) { s[c] = 0.f; q[c] = 0.f; }
  for (int rr = 0; rr < 4; ++rr) {
    int row = bl * 1024 + rr * 256 + t;
#pragma unroll
    for (int c = 0; c < 16; ++c) {
      float v = base[(size_t)row * 16 + c];
      s[c] += v; q[c] += v * v;
    }
  }
  __shared__ float sbs[256][16];
  __shared__ float sbq[256][16];
#pragma unroll
  for (int c = 0; c < 16; ++c) { sbs[t][c] = s[c]; sbq[t][c] = q[c]; }
  __syncthreads();
  for (int st = 128; st > 0; st >>= 1) {
    if (t < st) {
#pragma unroll
      for (int c = 0; c < 16; ++c) { sbs[t][c] += sbs[t + st][c]; sbq[t][c] += sbq[t + st][c]; }
    }
    __syncthreads();
  }
  if (t < 16) {
    part[(size_t)(br * 64 + bl) * 32 + t] = sbs[0][t];
    part[(size_t)(br * 64 + bl) * 32 + 16 + t] = sbq[0][t];
  }
}

__global__ void stats16_final(const float* __restrict__ part, float* __restrict__ stats) {
  int t = threadIdx.x;
  if (t < 32) {
    int br = t >> 4, c = t & 15;
    float s = 0.f, q = 0.f;
    for (int bl = 0; bl < 64; ++bl) {
      s += part[(size_t)(br * 64 + bl) * 32 + c];
      q += part[(size_t)(br * 64 + bl) * 32 + 16 + c];
    }
    float m = s / 65536.f;
    float var = q / 65536.f - m * m;
    stats[(br * 16 + c) * 2] = m;
    stats[(br * 16 + c) * 2 + 1] = rsqrtf(var + 1e-5f);
  }
}

// ---------------------------------------------------------------------------
// relu(bn(a1)) @ w_second  (16 -> 16), in-place over abuf
// ---------------------------------------------------------------------------
__global__ void mlp2_kernel(float* __restrict__ abuf, const float* __restrict__ stats,
                            const float* __restrict__ g00, const float* __restrict__ b00,
                            const float* __restrict__ g10, const float* __restrict__ b10,
                            const float* __restrict__ w01, const float* __restrict__ w11) {
  int gid = blockIdx.x * 256 + threadIdx.x;
  int br = gid >> 16;
  __shared__ float wl[256];
  wl[threadIdx.x] = (br ? w11 : w01)[threadIdx.x];
  __syncthreads();
  const float* g = br ? g10 : g00;
  const float* bb = br ? b10 : b00;
  float* row = abuf + (size_t)gid * 16;
  float z[16];
#pragma unroll
  for (int f = 0; f < 16; ++f) {
    float m = stats[(br * 16 + f) * 2], is = stats[(br * 16 + f) * 2 + 1];
    z[f] = fmaxf(0.f, (row[f] - m) * is * g[f] + bb[f]);
  }
  float o[16];
#pragma unroll
  for (int c = 0; c < 16; ++c) o[c] = 0.f;
#pragma unroll
  for (int f = 0; f < 16; ++f) {
#pragma unroll
    for (int c = 0; c < 16; ++c) o[c] += z[f] * wl[f * 16 + c];
  }
#pragma unroll
  for (int c = 0; c < 16; ++c) row[c] = o[c];
}

// ---------------------------------------------------------------------------
// relu(bn(a2)) max-pool over 16 samples -> feat columns [256, 288)
// ---------------------------------------------------------------------------
__global__ void pool_kernel(const float* __restrict__ abuf, const float* __restrict__ stats,
                            const int* __restrict__ cnts,
                            const float* __restrict__ g01, const float* __restrict__ b01,
                            const float* __restrict__ g11, const float* __restrict__ b11,
                            float* __restrict__ feat) {
  int gid = blockIdx.x * 256 + threadIdx.x;   // 131072
  int br = gid >> 16;
  int rem = gid & 65535;
  int bkp = rem >> 4, c = rem & 15;
  const float* g = br ? g11 : g01;
  const float* bb = br ? b11 : b01;
  float m = stats[(br * 16 + c) * 2], is = stats[(br * 16 + c) * 2 + 1];
  float gg = g[c], bv = bb[c];
  const float* base = abuf + ((size_t)br * 65536 + (size_t)bkp * 16) * 16 + c;
  float mx = -1e30f;
#pragma unroll
  for (int s = 0; s < 16; ++s) {
    float v = base[(size_t)s * 16];
    mx = fmaxf(mx, fmaxf(0.f, (v - m) * is * gg + bv));
  }
  if (cnts[br * M_ROWS + bkp] == 0) mx = 0.f;
  feat[(size_t)bkp * FEAT_DIM + 256 + br * 16 + c] = mx;
}

// ---------------------------------------------------------------------------
// Final matmul feat(4096x288) @ wf(288x128)
// ---------------------------------------------------------------------------
__global__ void final_mm(const float* __restrict__ feat, const float* __restrict__ wf,
                         float* __restrict__ hbuf) {
  int row = blockIdx.x;
  int c = threadIdx.x;   // 128
  __shared__ float fr[FEAT_DIM];
  for (int k = c; k < FEAT_DIM; k += 128) fr[k] = feat[(size_t)row * FEAT_DIM + k];
  __syncthreads();
  float acc = 0.f;
#pragma unroll 8
  for (int k = 0; k < FEAT_DIM; ++k) acc += fr[k] * wf[(size_t)k * C_OUT + c];
  hbuf[(size_t)row * C_OUT + c] = acc;
}

__global__ void stats128_partial(const float* __restrict__ hbuf, float* __restrict__ part) {
  int bl = blockIdx.x, c = threadIdx.x;  // 32 blocks x 128 thr
  float s = 0.f, q = 0.f;
  for (int r = 0; r < 128; ++r) {
    float v = hbuf[(size_t)(bl * 128 + r) * C_OUT + c];
    s += v; q += v * v;
  }
  part[(size_t)(bl * 128 + c) * 2] = s;
  part[(size_t)(bl * 128 + c) * 2 + 1] = q;
}

__global__ void stats128_final(const float* __restrict__ part, float* __restrict__ stats) {
  int c = threadIdx.x;  // 128
  float s = 0.f, q = 0.f;
  for (int bl = 0; bl < 32; ++bl) {
    s += part[(size_t)(bl * 128 + c) * 2];
    q += part[(size_t)(bl * 128 + c) * 2 + 1];
  }
  float m = s / 4096.f;
  float var = q / 4096.f - m * m;
  stats[c * 2] = m;
  stats[c * 2 + 1] = rsqrtf(var + 1e-5f);
}

// Output is FLOAT32 (reference returns relu(h) in fp32).
__global__ void out_kernel(const float* __restrict__ hbuf, const float* __restrict__ stats,
                           const float* __restrict__ gf, const float* __restrict__ bf,
                           float* __restrict__ out) {
  int gid = blockIdx.x * 256 + threadIdx.x;  // 524288
  int c = gid & 127;
  float v = hbuf[gid];
  float r = fmaxf(0.f, (v - stats[c * 2]) * stats[c * 2 + 1] * gf[c] + bf[c]);
  out[gid] = r;
}

// ---------------------------------------------------------------------------
extern "C" void kernel_launch(void* const* d_in, const int* in_sizes, int n_in,
                              void* d_out, int out_size, void* d_ws, size_t ws_size,
                              hipStream_t stream) {
  const float4* pts = (const float4*)d_in[0];
  const float* spatial = (const float*)d_in[1];
  const float* w0_0 = (const float*)d_in[2];
  const float* g0_0 = (const float*)d_in[3];
  const float* b0_0 = (const float*)d_in[4];
  const float* w0_1 = (const float*)d_in[5];
  const float* g0_1 = (const float*)d_in[6];
  const float* b0_1 = (const float*)d_in[7];
  const float* w1_0 = (const float*)d_in[8];
  const float* g1_0 = (const float*)d_in[9];
  const float* b1_0 = (const float*)d_in[10];
  const float* w1_1 = (const float*)d_in[11];
  const float* g1_1 = (const float*)d_in[12];
  const float* b1_1 = (const float*)d_in[13];
  const float* wf  = (const float*)d_in[14];
  const float* gf  = (const float*)d_in[15];
  const float* bfp = (const float*)d_in[16];
  const int* stride_p = (const int*)d_in[17];

  char* ws = (char*)d_ws;
  float4* kp_xyz = (float4*)(ws + 0);                 //  65536 B
  int* lists     = (int*)(ws + 65536);                // 524288 B
  int* cnts      = (int*)(ws + 589824);               //  32768 B
  float* abuf    = (float*)(ws + 622592);             // 8388608 B
  float* feat    = (float*)(ws + 9011200);            // 4718592 B
  float* hbuf    = (float*)(ws + 13729792);           // 2097152 B
  float* part16  = (float*)(ws + 15826944);           //  16384 B
  float* stats16 = (float*)(ws + 15843328);           //    256 B
  float* part128 = (float*)(ws + 15843584);           //  32768 B
  float* stats128= (float*)(ws + 15876352);           //   1024 B

  // Sort scratch OVERLAYS abuf (dead until group_mlp1, which runs after fps).
  char* sbase = (char*)abuf;
  float4* spts = (float4*)(sbase + 0);                // 1048576 B
  int* codes   = (int*)(sbase + 1048576);             //  262144 B
  int* counts  = (int*)(sbase + 1310720);             //   32768 B
  int* offs    = (int*)(sbase + 1343488);             //   32768 B
  float* bboxg = (float*)(sbase + 1376256);           //   24576 B

  cell_count<<<B_SZ, 1024, 0, stream>>>(pts, codes, counts);
  cell_scan<<<B_SZ, 64, 0, stream>>>(counts, offs);
  scatter_pts<<<B_SZ, 1024, 0, stream>>>(pts, codes, offs, spts);
  chunk_sort<<<256, 256, 0, stream>>>(spts);
  chunk_bbox<<<256, 256, 0, stream>>>(spts, bboxg);
  fps_pruned<<<B_SZ, 512, 0, stream>>>(pts, spts, bboxg, kp_xyz);
  bev_kernel<<<M_ROWS, 256, 0, stream>>>(kp_xyz, spatial, stride_p, feat);
  ballq_kernel<<<256, 256, 0, stream>>>(pts, kp_xyz, lists, cnts);
  group_mlp1<<<512, 256, 0, stream>>>(pts, kp_xyz, lists, cnts, w0_0, w1_0, abuf);
  stats16_partial<<<dim3(64, 2), 256, 0, stream>>>(abuf, part16);
  stats16_final<<<1, 64, 0, stream>>>(part16, stats16);
  mlp2_kernel<<<512, 256, 0, stream>>>(abuf, stats16, g0_0, b0_0, g1_0, b1_0, w0_1, w1_1);
  stats16_partial<<<dim3(64, 2), 256, 0, stream>>>(abuf, part16);
  stats16_final<<<1, 64, 0, stream>>>(part16, stats16);
  pool_kernel<<<512, 256, 0, stream>>>(abuf, stats16, cnts, g0_1, b0_1, g1_1, b1_1, feat);
  final_mm<<<M_ROWS, 128, 0, stream>>>(feat, wf, hbuf);
  stats128_partial<<<32, 128, 0, stream>>>(hbuf, part128);
  stats128_final<<<1, 128, 0, stream>>>(part128, stats128);
  out_kernel<<<2048, 256, 0, stream>>>(hbuf, stats128, gf, bfp, (float*)d_out);
}